// Round 5
// baseline (1202.090 us; speedup 1.0000x reference)
//
#include <hip/hip_runtime.h>
#include <hip/hip_bf16.h>

#define DEVI __device__ __forceinline__

typedef __attribute__((ext_vector_type(8))) short short8;
typedef __attribute__((ext_vector_type(4))) float f32x4;
typedef unsigned int u32;
typedef unsigned short u16;

typedef __attribute__((address_space(1))) const u32 gu32_t;
typedef __attribute__((address_space(3))) u32 lu32_t;

DEVI u16 f2bf(float f) {
  u32 u = __builtin_bit_cast(u32, f);
  u32 r = (u + 0x7fffu + ((u >> 16) & 1u)) >> 16;
  return (u16)r;
}

DEVI f32x4 mfma16(short8 a, short8 b, f32x4 c) {
  return __builtin_amdgcn_mfma_f32_16x16x32_bf16(a, b, c, 0, 0, 0);
}

DEVI void gload16(const void* g, void* l) {
  __builtin_amdgcn_global_load_lds((gu32_t*)g, (lu32_t*)l, 16, 0, 0);
}

#define CHUNK_ROWS 25088   // 512 windows * 49 tokens
#define PLANE ((size_t)CHUNK_ROWS * 64)
#define KOFF  ((size_t)8 * PLANE)          // k planes base
#define VOFF  ((size_t)16 * PLANE)         // v planes base (linear)

// ---------------- weight f32 -> bf16 ----------------
__global__ __launch_bounds__(256) void convk(const float* __restrict__ s, u16* __restrict__ d, int n4) {
  int i = blockIdx.x * 256 + threadIdx.x;
  if (i < n4) {
    const float4 v = ((const float4*)s)[i];
    ushort4 o;
    o.x = f2bf(v.x); o.y = f2bf(v.y); o.z = f2bf(v.z); o.w = f2bf(v.w);
    ((ushort4*)d)[i] = o;
  }
}

// ---------------- LN1 + shift + window gather -> XY bf16 [CHUNK_ROWS][512] ----------------
__global__ __launch_bounds__(256) void ln_gather(
    const float* __restrict__ x, const float* __restrict__ y,
    const float* __restrict__ g1, const float* __restrict__ b1,
    u16* __restrict__ XY, int rowbase)
{
  const int wv = threadIdx.x >> 6, lane = threadIdx.x & 63;
  const int rl = blockIdx.x * 4 + wv;
  const int row = rowbase + rl;
  const int w = row / 49, n = row - w * 49;
  const int b = w >> 6, win = w & 63, wh = win >> 3, ww = win & 7;
  const int r = n / 7, c = n - r * 7;
  int oh = wh * 7 + r + 3; if (oh >= 56) oh -= 56;
  int ow = ww * 7 + c + 3; if (ow >= 56) ow -= 56;
  const size_t po = ((size_t)b * 3136 + oh * 56 + ow) * 256;
  const float4 g1v = ((const float4*)g1)[lane];
  const float4 b1v = ((const float4*)b1)[lane];
  u16* orow = XY + (size_t)rl * 512;
  #pragma unroll
  for (int mod = 0; mod < 2; ++mod) {
    const float* src = (mod ? y : x) + po;
    const float4 v = ((const float4*)src)[lane];
    float s = v.x + v.y + v.z + v.w;
    #pragma unroll
    for (int off = 1; off < 64; off <<= 1) s += __shfl_xor(s, off);
    const float mean = s * (1.0f / 256.0f);
    const float d0 = v.x - mean, d1 = v.y - mean, d2 = v.z - mean, d3 = v.w - mean;
    float sq = d0 * d0 + d1 * d1 + d2 * d2 + d3 * d3;
    #pragma unroll
    for (int off = 1; off < 64; off <<= 1) sq += __shfl_xor(sq, off);
    const float rstd = rsqrtf(sq * (1.0f / 256.0f) + 1e-5f);
    ushort4 o;
    o.x = f2bf(d0 * rstd * g1v.x + b1v.x);
    o.y = f2bf(d1 * rstd * g1v.y + b1v.y);
    o.z = f2bf(d2 * rstd * g1v.z + b1v.z);
    o.w = f2bf(d3 * rstd * g1v.w + b1v.w);
    *(ushort4*)(orow + mod * 256 + lane * 4) = o;
  }
}

// ---------------- QKV GEMM (BM=256, BN=128, XCD-swizzled): M=25088, N=1536, K=512 ----------------
__global__ __launch_bounds__(256, 2) void qkv_gemm(
    const u16* __restrict__ A, const u16* __restrict__ Bw,
    const float* __restrict__ bias, u16* __restrict__ Qo)
{
  __shared__ __align__(16) u16 sA[256 * 64];
  __shared__ __align__(16) u16 sB[128 * 64];
  const int nx = gridDim.x;
  const int nwg = nx * gridDim.y;
  const int orig = blockIdx.y * nx + blockIdx.x;
  const int sw = (orig & 7) * (nwg >> 3) + (orig >> 3);
  const int nn0 = (sw % nx) * 128;
  const int m0  = (sw / nx) * 256;
  const int tid = threadIdx.x;
  const int lane = tid & 63;
  const int wv = tid >> 6;
  const int wm = wv >> 1, wn = wv & 1;
  const int rq = lane & 15, kg = lane >> 4;
  f32x4 acc[8][4];
  #pragma unroll
  for (int i = 0; i < 8; ++i)
    #pragma unroll
    for (int j = 0; j < 4; ++j) acc[i][j] = f32x4{0,0,0,0};

  for (int kt = 0; kt < 8; ++kt) {
    if (kt) __syncthreads();
    #pragma unroll
    for (int i = 0; i < 8; ++i) {
      const int c = i * 256 + tid;
      gload16(A + (size_t)(m0 + (c >> 3)) * 512 + kt * 64 + (c & 7) * 8, sA + c * 8);
    }
    #pragma unroll
    for (int i = 0; i < 4; ++i) {
      const int c = i * 256 + tid;
      gload16(Bw + (size_t)(nn0 + (c >> 3)) * 512 + kt * 64 + (c & 7) * 8, sB + c * 8);
    }
    __syncthreads();
    #pragma unroll
    for (int k0 = 0; k0 < 2; ++k0) {
      short8 bf8[4];
      #pragma unroll
      for (int nt = 0; nt < 4; ++nt)
        bf8[nt] = *(const short8*)(sB + (wn * 64 + nt * 16 + rq) * 64 + k0 * 32 + kg * 8);
      #pragma unroll
      for (int mt = 0; mt < 8; ++mt) {
        const short8 af = *(const short8*)(sA + (wm * 128 + mt * 16 + rq) * 64 + k0 * 32 + kg * 8);
        #pragma unroll
        for (int nt = 0; nt < 4; ++nt)
          acc[mt][nt] = mfma16(af, bf8[nt], acc[mt][nt]);
      }
    }
  }
  #pragma unroll
  for (int mt = 0; mt < 8; ++mt) {
    #pragma unroll
    for (int nt = 0; nt < 4; ++nt) {
      const int col = nn0 + wn * 64 + nt * 16 + rq;
      const int t = col >> 9, rem = col & 511;
      const int h = rem >> 6, d = rem & 63;
      const float bc = bias[col];
      const float sc = (t == 0) ? 0.17677669529663687f : 1.0f;
      u16* bp = Qo + (size_t)(t * 8 + h) * PLANE + d;
      #pragma unroll
      for (int r = 0; r < 4; ++r) {
        const int row = m0 + wm * 128 + mt * 16 + kg * 4 + r;
        bp[(size_t)row * 64] = f2bf((acc[mt][nt][r] + bc) * sc);
      }
    }
  }
}

// ---------------- barrier-free attention: one wave per (window, head) ----------------
// v staged per-wave into LDS as vT[d][tok^swz] (stride 72) -> PV B-frags are b128 reads.
__global__ __launch_bounds__(256, 3) void attn3(
    const u16* __restrict__ qkv, const float* __restrict__ rpb,
    u16* __restrict__ concat, int wbase)
{
  __shared__ __align__(16) u16 sP[4][3136];    // per-wave P / out buffer (49 x 64, swizzled)
  __shared__ __align__(16) u16 sVT[4][4608];   // per-wave vT: [d][tok^((d>>3)&3)<<4], stride 72
  __shared__ float sRpb[4][169];

  const int tid = threadIdx.x;
  const int wv = tid >> 6, lane = tid & 63;
  const int rq = lane & 15, kg = lane >> 4;
  const int gw = blockIdx.x * 4 + wv;
  const int wl = gw >> 3, h = gw & 7;
  const int w = wbase + wl;
  const int win = w & 63, wh = win >> 3, ww = win & 7;
  const bool edge = (wh == 7) || (ww == 7);
  u16* sPw = sP[wv];
  u16* sVw = sVT[wv];

  for (int e = lane; e < 169; e += 64) sRpb[wv][e] = rpb[e * 8 + h];

  const u16* qbase = qkv + (size_t)h * PLANE + (size_t)wl * 49 * 64;
  const u16* kbase = qkv + KOFF + (size_t)h * PLANE + (size_t)wl * 49 * 64;
  const u16* vbase = qkv + VOFF + (size_t)h * PLANE + (size_t)wl * 49 * 64;

  // ---- issue v row loads early (hidden under QK^T) ----
  short8 vreg[4][2];
  #pragma unroll
  for (int t = 0; t < 4; ++t)
    #pragma unroll
    for (int h2 = 0; h2 < 2; ++h2)
      vreg[t][h2] = *(const short8*)(vbase + (size_t)(16 * t + rq) * 64 + kg * 8 + h2 * 32);

  // ---- K fragments (all), then S with per-i Q loads ----
  short8 ak[4][2];
  #pragma unroll
  for (int j = 0; j < 4; ++j) {
    const int rr = (16 * j + rq) > 48 ? 48 : (16 * j + rq);
    ak[j][0] = *(const short8*)(kbase + rr * 64 + kg * 8);
    ak[j][1] = *(const short8*)(kbase + rr * 64 + 32 + kg * 8);
  }
  f32x4 sacc[4][4];
  #pragma unroll
  for (int i = 0; i < 4; ++i)
    #pragma unroll
    for (int j = 0; j < 4; ++j) sacc[i][j] = f32x4{0,0,0,0};
  #pragma unroll
  for (int i = 0; i < 4; ++i) {
    const int rr = (16 * i + rq) > 48 ? 48 : (16 * i + rq);
    const short8 a0 = *(const short8*)(qbase + rr * 64 + kg * 8);
    const short8 a1 = *(const short8*)(qbase + rr * 64 + 32 + kg * 8);
    #pragma unroll
    for (int j = 0; j < 4; ++j) {
      sacc[i][j] = mfma16(a0, ak[j][0], sacc[i][j]);
      sacc[i][j] = mfma16(a1, ak[j][1], sacc[i][j]);
    }
  }

  // ---- write v into LDS vT (conflict-free: row ^ (kg<<4)) ----
  #pragma unroll
  for (int t = 0; t < 4; ++t) {
    const int row = 16 * t + rq;
    #pragma unroll
    for (int h2 = 0; h2 < 2; ++h2) {
      const int c0 = kg * 8 + h2 * 32;
      #pragma unroll
      for (int j = 0; j < 8; ++j)
        sVw[(c0 + j) * 72 + (row ^ (kg << 4))] = (u16)vreg[t][h2][j];
    }
  }

  // ---- bias + mask + softmax; P -> sPw (swizzled) ----
  #pragma unroll
  for (int i = 0; i < 4; ++i) {
    #pragma unroll
    for (int r = 0; r < 4; ++r) {
      const int n = 16 * i + kg * 4 + r;
      const bool nv = n < 49;
      const int r1 = n / 7, c1 = n - r1 * 7;
      int reg1 = 0;
      if (edge && nv) {
        const int sh1 = wh * 7 + r1, sw1 = ww * 7 + c1;
        reg1 = (sh1 < 49 ? 0 : (sh1 < 53 ? 1 : 2)) * 3 + (sw1 < 49 ? 0 : (sw1 < 53 ? 1 : 2));
      }
      float pv[4];
      #pragma unroll
      for (int j = 0; j < 4; ++j) {
        const int m = 16 * j + rq;
        float sv = -1e30f;
        if (nv && m < 49) {
          const int r2 = m / 7, c2 = m - r2 * 7;
          const int rel = (r1 - r2 + 6) * 13 + (c1 - c2 + 6);
          float msk = 0.f;
          if (edge) {
            const int sh2 = wh * 7 + r2, sw2 = ww * 7 + c2;
            const int reg2 = (sh2 < 49 ? 0 : (sh2 < 53 ? 1 : 2)) * 3 + (sw2 < 49 ? 0 : (sw2 < 53 ? 1 : 2));
            msk = (reg1 == reg2) ? 0.f : -100.f;
          }
          sv = sacc[i][j][r] + sRpb[wv][rel] + msk;
        }
        pv[j] = sv;
      }
      float mx = fmaxf(fmaxf(pv[0], pv[1]), fmaxf(pv[2], pv[3]));
      #pragma unroll
      for (int off = 1; off < 16; off <<= 1) mx = fmaxf(mx, __shfl_xor(mx, off));
      float sm = 0.f;
      #pragma unroll
      for (int j = 0; j < 4; ++j) { const float e = __expf(pv[j] - mx); pv[j] = e; sm += e; }
      #pragma unroll
      for (int off = 1; off < 16; off <<= 1) sm += __shfl_xor(sm, off);
      const float inv = 1.0f / sm;
      if (nv) {
        #pragma unroll
        for (int j = 0; j < 4; ++j) {
          const int col = 16 * j + rq;
          sPw[n * 64 + (((col >> 3) ^ (n & 7)) << 3) + (col & 7)] = f2bf(pv[j] * inv);
        }
      }
    }
  }

  // ---- PV: A = P (LDS), B = vT (LDS b128, pad toks masked) ----
  f32x4 oacc[4][4];
  #pragma unroll
  for (int i = 0; i < 4; ++i)
    #pragma unroll
    for (int j = 0; j < 4; ++j) oacc[i][j] = f32x4{0,0,0,0};
  #pragma unroll
  for (int m0v = 0; m0v < 2; ++m0v) {
    short8 av[4];
    #pragma unroll
    for (int ct = 0; ct < 4; ++ct) {
      const int col = ct * 16 + rq;
      const int s = (col >> 3) & 3;
      short8 vvv = *(const short8*)(sVw + col * 72 + ((m0v * 32 + kg * 8) ^ (s << 4)));
      if (m0v == 1) {
        if (kg == 3) {
          #pragma unroll
          for (int e = 0; e < 8; ++e) vvv[e] = 0;        // tokens 56..63: pad
        } else if (kg == 2) {
          #pragma unroll
          for (int e = 1; e < 8; ++e) vvv[e] = 0;        // tokens 49..55: pad
        }
      }
      av[ct] = vvv;
    }
    #pragma unroll
    for (int i = 0; i < 4; ++i) {
      const int rr = (16 * i + rq) > 48 ? 48 : (16 * i + rq);
      const int ch = (m0v * 4 + kg) ^ (rr & 7);
      const short8 pa = *(const short8*)(sPw + rr * 64 + ch * 8);
      #pragma unroll
      for (int ct = 0; ct < 4; ++ct)
        oacc[i][ct] = mfma16(pa, av[ct], oacc[i][ct]);
    }
  }

  // ---- repack out_h through LDS (reuse sPw), coalesced b128 store ----
  __builtin_amdgcn_s_waitcnt(0);  // wave-local LDS reuse: P reads done (single wave)
  #pragma unroll
  for (int i = 0; i < 4; ++i)
    #pragma unroll
    for (int ct = 0; ct < 4; ++ct)
      #pragma unroll
      for (int r = 0; r < 4; ++r) {
        const int n = 16 * i + kg * 4 + r;
        if (n < 49) {
          const int col = ct * 16 + rq;
          sPw[n * 64 + (((col >> 3) ^ (n & 7)) << 3) + (col & 7)] = f2bf(oacc[i][ct][r]);
        }
      }
  u16* crow = concat + (size_t)(wl * 49) * 512 + h * 64;
  #pragma unroll
  for (int it = 0; it < 7; ++it) {
    const int c = it * 64 + lane;
    if (c < 392) {
      const int m = c >> 3, s = c & 7;
      const short8 vvv = *(const short8*)(sPw + m * 64 + ((s ^ (m & 7)) << 3));
      *(short8*)(crow + (size_t)m * 512 + s * 8) = vvv;
    }
  }
}

// ---------------- proj GEMM + LN2 fused: BM=128, BN=256 (full row); grid 196 ----------------
__global__ __launch_bounds__(256, 2) void projln(
    const u16* __restrict__ A, const u16* __restrict__ Bw,
    const float* __restrict__ bias, const float* __restrict__ x,
    const float* __restrict__ g2, const float* __restrict__ b2,
    float* __restrict__ out, u16* __restrict__ xn2, int rowbase)
{
  __shared__ __align__(16) u16 sA[128 * 64];
  __shared__ __align__(16) u16 sB[256 * 64];
  const int m0 = blockIdx.x * 128;
  const int tid = threadIdx.x;
  const int lane = tid & 63;
  const int wv = tid >> 6;
  const int rq = lane & 15, kg = lane >> 4;
  f32x4 acc[2][16];
  #pragma unroll
  for (int i = 0; i < 2; ++i)
    #pragma unroll
    for (int j = 0; j < 16; ++j) acc[i][j] = f32x4{0,0,0,0};

  for (int kt = 0; kt < 8; ++kt) {
    if (kt) __syncthreads();
    #pragma unroll
    for (int i = 0; i < 4; ++i) {
      const int c = i * 256 + tid;
      gload16(A + (size_t)(m0 + (c >> 3)) * 512 + kt * 64 + (c & 7) * 8, sA + c * 8);
    }
    #pragma unroll
    for (int i = 0; i < 8; ++i) {
      const int c = i * 256 + tid;
      gload16(Bw + (size_t)(c >> 3) * 512 + kt * 64 + (c & 7) * 8, sB + c * 8);
    }
    __syncthreads();
    #pragma unroll
    for (int k0 = 0; k0 < 2; ++k0) {
      short8 af[2];
      #pragma unroll
      for (int mt = 0; mt < 2; ++mt)
        af[mt] = *(const short8*)(sA + (wv * 32 + mt * 16 + rq) * 64 + k0 * 32 + kg * 8);
      #pragma unroll
      for (int nt = 0; nt < 16; ++nt) {
        const short8 bf8 = *(const short8*)(sB + (nt * 16 + rq) * 64 + k0 * 32 + kg * 8);
        #pragma unroll
        for (int mt = 0; mt < 2; ++mt)
          acc[mt][nt] = mfma16(af[mt], bf8, acc[mt][nt]);
      }
    }
  }

  float br[16], g2r[16], b2r[16];
  #pragma unroll
  for (int nt = 0; nt < 16; ++nt) {
    const int col = nt * 16 + rq;
    br[nt] = bias[col]; g2r[nt] = g2[col]; b2r[nt] = b2[col];
  }
  #pragma unroll
  for (int mt = 0; mt < 2; ++mt) {
    #pragma unroll
    for (int r = 0; r < 4; ++r) {
      const int row = m0 + wv * 32 + mt * 16 + kg * 4 + r;
      const u32 g = (u32)(rowbase + row);
      const u32 w = g / 49u; const u32 n = g - w * 49u;
      const int b = w >> 6, win = w & 63, wh = win >> 3, ww = win & 7;
      const u32 rr = n / 7u; const u32 cc = n - rr * 7u;
      int oh = wh * 7 + (int)rr + 3; if (oh >= 56) oh -= 56;
      int ow = ww * 7 + (int)cc + 3; if (ow >= 56) ow -= 56;
      const size_t po = ((size_t)b * 3136 + oh * 56 + ow) * 256;
      float vals[16];
      float s = 0.f;
      #pragma unroll
      for (int nt = 0; nt < 16; ++nt) {
        const float v = acc[mt][nt][r] + br[nt] + x[po + nt * 16 + rq];
        vals[nt] = v; s += v;
      }
      #pragma unroll
      for (int off = 1; off < 16; off <<= 1) s += __shfl_xor(s, off);
      const float mean = s * (1.0f / 256.0f);
      float sq = 0.f;
      #pragma unroll
      for (int nt = 0; nt < 16; ++nt) { const float d_ = vals[nt] - mean; sq += d_ * d_; }
      #pragma unroll
      for (int off = 1; off < 16; off <<= 1) sq += __shfl_xor(sq, off);
      const float rstd = rsqrtf(sq * (1.0f / 256.0f) + 1e-5f);
      #pragma unroll
      for (int nt = 0; nt < 16; ++nt) {
        const int col = nt * 16 + rq;
        out[po + col] = vals[nt];
        xn2[po + col] = f2bf((vals[nt] - mean) * rstd * g2r[nt] + b2r[nt]);
      }
    }
  }
}

// ---------------- FC1 (BM=256, BN=128, XCD-swizzled): M=25088, N=1024, K=256, GELU ----------------
__global__ __launch_bounds__(256, 2) void fc1_gemm(
    const u16* __restrict__ A, const u16* __restrict__ Bw,
    const float* __restrict__ bias, u16* __restrict__ obf)
{
  __shared__ __align__(16) u16 sA[256 * 64];
  __shared__ __align__(16) u16 sB[128 * 64];
  const int nx = gridDim.x;
  const int nwg = nx * gridDim.y;
  const int orig = blockIdx.y * nx + blockIdx.x;
  const int sw = (orig & 7) * (nwg >> 3) + (orig >> 3);
  const int nn0 = (sw % nx) * 128;
  const int m0  = (sw / nx) * 256;
  const int tid = threadIdx.x;
  const int lane = tid & 63;
  const int wv = tid >> 6;
  const int wm = wv >> 1, wn = wv & 1;
  const int rq = lane & 15, kg = lane >> 4;
  f32x4 acc[8][4];
  #pragma unroll
  for (int i = 0; i < 8; ++i)
    #pragma unroll
    for (int j = 0; j < 4; ++j) acc[i][j] = f32x4{0,0,0,0};

  for (int kt = 0; kt < 4; ++kt) {
    if (kt) __syncthreads();
    #pragma unroll
    for (int i = 0; i < 8; ++i) {
      const int c = i * 256 + tid;
      gload16(A + (size_t)(m0 + (c >> 3)) * 256 + kt * 64 + (c & 7) * 8, sA + c * 8);
    }
    #pragma unroll
    for (int i = 0; i < 4; ++i) {
      const int c = i * 256 + tid;
      gload16(Bw + (size_t)(nn0 + (c >> 3)) * 256 + kt * 64 + (c & 7) * 8, sB + c * 8);
    }
    __syncthreads();
    #pragma unroll
    for (int k0 = 0; k0 < 2; ++k0) {
      short8 bf8[4];
      #pragma unroll
      for (int nt = 0; nt < 4; ++nt)
        bf8[nt] = *(const short8*)(sB + (wn * 64 + nt * 16 + rq) * 64 + k0 * 32 + kg * 8);
      #pragma unroll
      for (int mt = 0; mt < 8; ++mt) {
        const short8 af = *(const short8*)(sA + (wm * 128 + mt * 16 + rq) * 64 + k0 * 32 + kg * 8);
        #pragma unroll
        for (int nt = 0; nt < 4; ++nt)
          acc[mt][nt] = mfma16(af, bf8[nt], acc[mt][nt]);
      }
    }
  }
  #pragma unroll
  for (int mt = 0; mt < 8; ++mt) {
    #pragma unroll
    for (int nt = 0; nt < 4; ++nt) {
      const int col = nn0 + wn * 64 + nt * 16 + rq;
      const float bcol = bias[col];
      #pragma unroll
      for (int r = 0; r < 4; ++r) {
        const int row = m0 + wm * 128 + mt * 16 + kg * 4 + r;
        float v = acc[mt][nt][r] + bcol;
        v = 0.5f * v * (1.0f + erff(v * 0.7071067811865476f));
        obf[(size_t)row * 1024 + col] = f2bf(v);
      }
    }
  }
}

// ---------------- FC2 (128x128): K=1024, N=256, + bias + residual ----------------
__global__ __launch_bounds__(256) void fc2_gemm(
    const u16* __restrict__ A, const u16* __restrict__ Bw,
    const float* __restrict__ bias, float* __restrict__ ofr)
{
  __shared__ __align__(16) u16 sA[128 * 64];
  __shared__ __align__(16) u16 sB[128 * 64];
  const int m0 = blockIdx.y * 128;
  const int nn0 = blockIdx.x * 128;
  const int tid = threadIdx.x;
  const int lane = tid & 63;
  const int wv = tid >> 6;
  const int wm = wv >> 1, wn = wv & 1;
  const int rq = lane & 15, kg = lane >> 4;
  f32x4 acc[4][4];
  #pragma unroll
  for (int i = 0; i < 4; ++i)
    #pragma unroll
    for (int j = 0; j < 4; ++j) acc[i][j] = f32x4{0,0,0,0};

  for (int kt = 0; kt < 16; ++kt) {
    if (kt) __syncthreads();
    #pragma unroll
    for (int i = 0; i < 4; ++i) {
      const int c = i * 256 + tid;
      gload16(A + (size_t)(m0 + (c >> 3)) * 1024 + kt * 64 + (c & 7) * 8, sA + c * 8);
    }
    #pragma unroll
    for (int i = 0; i < 4; ++i) {
      const int c = i * 256 + tid;
      gload16(Bw + (size_t)(nn0 + (c >> 3)) * 1024 + kt * 64 + (c & 7) * 8, sB + c * 8);
    }
    __syncthreads();
    #pragma unroll
    for (int k0 = 0; k0 < 2; ++k0) {
      short8 af[4], bf8[4];
      #pragma unroll
      for (int mt = 0; mt < 4; ++mt)
        af[mt] = *(const short8*)(sA + (wm * 64 + mt * 16 + rq) * 64 + k0 * 32 + kg * 8);
      #pragma unroll
      for (int nt = 0; nt < 4; ++nt)
        bf8[nt] = *(const short8*)(sB + (wn * 64 + nt * 16 + rq) * 64 + k0 * 32 + kg * 8);
      #pragma unroll
      for (int mt = 0; mt < 4; ++mt)
        #pragma unroll
        for (int nt = 0; nt < 4; ++nt)
          acc[mt][nt] = mfma16(af[mt], bf8[nt], acc[mt][nt]);
    }
  }
  #pragma unroll
  for (int mt = 0; mt < 4; ++mt) {
    #pragma unroll
    for (int nt = 0; nt < 4; ++nt) {
      const int col = nn0 + wn * 64 + nt * 16 + rq;
      const float bcol = bias[col];
      #pragma unroll
      for (int r = 0; r < 4; ++r) {
        const int row = m0 + wm * 64 + mt * 16 + kg * 4 + r;
        float* p = ofr + (size_t)row * 256 + col;
        *p = acc[mt][nt][r] + bcol + *p;
      }
    }
  }
}

extern "C" void kernel_launch(void* const* d_in, const int* in_sizes, int n_in,
                              void* d_out, int out_size, void* d_ws, size_t ws_size,
                              hipStream_t stream) {
  const float* x      = (const float*)d_in[0];
  const float* y      = (const float*)d_in[1];
  const float* g1     = (const float*)d_in[2];
  const float* b1     = (const float*)d_in[3];
  const float* rpb    = (const float*)d_in[4];
  const float* w_qkv  = (const float*)d_in[5];
  const float* b_qkv  = (const float*)d_in[6];
  const float* w_proj = (const float*)d_in[7];
  const float* b_proj = (const float*)d_in[8];
  const float* g2     = (const float*)d_in[9];
  const float* b2     = (const float*)d_in[10];
  const float* w_fc1  = (const float*)d_in[11];
  const float* b_fc1  = (const float*)d_in[12];
  const float* w_fc2  = (const float*)d_in[13];
  const float* b_fc2  = (const float*)d_in[14];
  float* out = (float*)d_out;

  u16* wsp = (u16*)d_ws;
  u16* wqkv_bf  = wsp;                       //  786432
  u16* wproj_bf = wsp + 786432;              //  131072
  u16* wfc1_bf  = wsp + 917504;              //  262144
  u16* wfc2_bf  = wsp + 1179648;             //  262144
  u16* xn2      = wsp + 1441792;             //  25690112
  u16* XYc      = wsp + 27131904;            //  12845056 (25088 x 512) XY, then concat
  u16* qkvc     = wsp + 39976960;            //  24 planes x 25088 x 64 (+ slack)
  u16* hbuf     = XYc;                       //  overlay (dead in MLP phase)

  convk<<<768, 256, 0, stream>>>(w_qkv,  wqkv_bf,  196608);
  convk<<<128, 256, 0, stream>>>(w_proj, wproj_bf, 32768);
  convk<<<256, 256, 0, stream>>>(w_fc1,  wfc1_bf,  65536);
  convk<<<256, 256, 0, stream>>>(w_fc2,  wfc2_bf,  65536);

  for (int c = 0; c < 4; ++c) {
    ln_gather<<<6272, 256, 0, stream>>>(x, y, g1, b1, XYc, c * CHUNK_ROWS);
    qkv_gemm<<<dim3(12, 98), 256, 0, stream>>>(XYc, wqkv_bf, b_qkv, qkvc);
    attn3<<<1024, 256, 0, stream>>>(qkvc, rpb, XYc, c * 512);
    projln<<<196, 256, 0, stream>>>(XYc, wproj_bf, b_proj, x, g2, b2, out, xn2, c * CHUNK_ROWS);
  }

  for (int c = 0; c < 4; ++c) {
    fc1_gemm<<<dim3(8, 98), 256, 0, stream>>>(
        xn2 + (size_t)c * CHUNK_ROWS * 256, wfc1_bf, b_fc1, hbuf);
    fc2_gemm<<<dim3(2, 196), 256, 0, stream>>>(
        hbuf, wfc2_bf, b_fc2, out + (size_t)c * CHUNK_ROWS * 256);
  }
}

// Round 6
// 1101.299 us; speedup vs baseline: 1.0915x; 1.0915x over previous
//
#include <hip/hip_runtime.h>
#include <hip/hip_bf16.h>

#define DEVI __device__ __forceinline__

typedef __attribute__((ext_vector_type(8))) short short8;
typedef __attribute__((ext_vector_type(4))) float f32x4;
typedef unsigned int u32;
typedef unsigned short u16;

typedef __attribute__((address_space(1))) const u32 gu32_t;
typedef __attribute__((address_space(3))) u32 lu32_t;

DEVI u16 f2bf(float f) {
  u32 u = __builtin_bit_cast(u32, f);
  u32 r = (u + 0x7fffu + ((u >> 16) & 1u)) >> 16;
  return (u16)r;
}

DEVI f32x4 mfma16(short8 a, short8 b, f32x4 c) {
  return __builtin_amdgcn_mfma_f32_16x16x32_bf16(a, b, c, 0, 0, 0);
}

DEVI void gload16(const void* g, void* l) {
  __builtin_amdgcn_global_load_lds((gu32_t*)g, (lu32_t*)l, 16, 0, 0);
}

#define CHUNK_ROWS 25088   // 512 windows * 49 tokens
#define PLANE ((size_t)CHUNK_ROWS * 64)
#define KOFF  ((size_t)8 * PLANE)          // k planes base
#define VOFF  ((size_t)16 * PLANE)         // v planes base (linear)

// ---------------- weight f32 -> bf16 ----------------
__global__ __launch_bounds__(256) void convk(const float* __restrict__ s, u16* __restrict__ d, int n4) {
  int i = blockIdx.x * 256 + threadIdx.x;
  if (i < n4) {
    const float4 v = ((const float4*)s)[i];
    ushort4 o;
    o.x = f2bf(v.x); o.y = f2bf(v.y); o.z = f2bf(v.z); o.w = f2bf(v.w);
    ((ushort4*)d)[i] = o;
  }
}

// ---------------- LN1 + shift + window gather -> XY bf16 [CHUNK_ROWS][512] ----------------
__global__ __launch_bounds__(256) void ln_gather(
    const float* __restrict__ x, const float* __restrict__ y,
    const float* __restrict__ g1, const float* __restrict__ b1,
    u16* __restrict__ XY, int rowbase)
{
  const int wv = threadIdx.x >> 6, lane = threadIdx.x & 63;
  const int rl = blockIdx.x * 4 + wv;
  const int row = rowbase + rl;
  const int w = row / 49, n = row - w * 49;
  const int b = w >> 6, win = w & 63, wh = win >> 3, ww = win & 7;
  const int r = n / 7, c = n - r * 7;
  int oh = wh * 7 + r + 3; if (oh >= 56) oh -= 56;
  int ow = ww * 7 + c + 3; if (ow >= 56) ow -= 56;
  const size_t po = ((size_t)b * 3136 + oh * 56 + ow) * 256;
  const float4 g1v = ((const float4*)g1)[lane];
  const float4 b1v = ((const float4*)b1)[lane];
  u16* orow = XY + (size_t)rl * 512;
  #pragma unroll
  for (int mod = 0; mod < 2; ++mod) {
    const float* src = (mod ? y : x) + po;
    const float4 v = ((const float4*)src)[lane];
    float s = v.x + v.y + v.z + v.w;
    #pragma unroll
    for (int off = 1; off < 64; off <<= 1) s += __shfl_xor(s, off);
    const float mean = s * (1.0f / 256.0f);
    const float d0 = v.x - mean, d1 = v.y - mean, d2 = v.z - mean, d3 = v.w - mean;
    float sq = d0 * d0 + d1 * d1 + d2 * d2 + d3 * d3;
    #pragma unroll
    for (int off = 1; off < 64; off <<= 1) sq += __shfl_xor(sq, off);
    const float rstd = rsqrtf(sq * (1.0f / 256.0f) + 1e-5f);
    ushort4 o;
    o.x = f2bf(d0 * rstd * g1v.x + b1v.x);
    o.y = f2bf(d1 * rstd * g1v.y + b1v.y);
    o.z = f2bf(d2 * rstd * g1v.z + b1v.z);
    o.w = f2bf(d3 * rstd * g1v.w + b1v.w);
    *(ushort4*)(orow + mod * 256 + lane * 4) = o;
  }
}

// ---------------- QKV GEMM (128x128, XCD-swizzled): M=25088, N=1536, K=512 ----------------
// grid (12, 196); swizzle gives each XCD a contiguous m-range (A L2-resident).
__global__ __launch_bounds__(256) void qkv_gemm(
    const u16* __restrict__ A, const u16* __restrict__ Bw,
    const float* __restrict__ bias, u16* __restrict__ Qo)
{
  __shared__ __align__(16) u16 sA[128 * 64];
  __shared__ __align__(16) u16 sB[128 * 64];
  const int nx = gridDim.x;
  const int nwg = nx * gridDim.y;
  const int orig = blockIdx.y * nx + blockIdx.x;
  const int sw = (orig & 7) * (nwg >> 3) + (orig >> 3);
  const int m0  = (sw / nx) * 128;
  const int nn0 = (sw % nx) * 128;
  const int tid = threadIdx.x;
  const int lane = tid & 63;
  const int wv = tid >> 6;
  const int wm = wv >> 1, wn = wv & 1;
  const int rq = lane & 15, kg = lane >> 4;
  f32x4 acc[4][4];
  #pragma unroll
  for (int i = 0; i < 4; ++i)
    #pragma unroll
    for (int j = 0; j < 4; ++j) acc[i][j] = f32x4{0,0,0,0};

  for (int kt = 0; kt < 8; ++kt) {
    if (kt) __syncthreads();
    #pragma unroll
    for (int i = 0; i < 4; ++i) {
      const int c = i * 256 + tid;
      gload16(A + (size_t)(m0 + (c >> 3)) * 512 + kt * 64 + (c & 7) * 8, sA + c * 8);
    }
    #pragma unroll
    for (int i = 0; i < 4; ++i) {
      const int c = i * 256 + tid;
      gload16(Bw + (size_t)(nn0 + (c >> 3)) * 512 + kt * 64 + (c & 7) * 8, sB + c * 8);
    }
    __syncthreads();
    #pragma unroll
    for (int k0 = 0; k0 < 2; ++k0) {
      short8 af[4], bf8[4];
      #pragma unroll
      for (int mt = 0; mt < 4; ++mt)
        af[mt] = *(const short8*)(sA + (wm * 64 + mt * 16 + rq) * 64 + k0 * 32 + kg * 8);
      #pragma unroll
      for (int nt = 0; nt < 4; ++nt)
        bf8[nt] = *(const short8*)(sB + (wn * 64 + nt * 16 + rq) * 64 + k0 * 32 + kg * 8);
      #pragma unroll
      for (int mt = 0; mt < 4; ++mt)
        #pragma unroll
        for (int nt = 0; nt < 4; ++nt)
          acc[mt][nt] = mfma16(af[mt], bf8[nt], acc[mt][nt]);
    }
  }
  #pragma unroll
  for (int mt = 0; mt < 4; ++mt) {
    #pragma unroll
    for (int nt = 0; nt < 4; ++nt) {
      const int col = nn0 + wn * 64 + nt * 16 + rq;
      const int t = col >> 9, rem = col & 511;
      const int h = rem >> 6, d = rem & 63;
      const float bc = bias[col];
      const float sc = (t == 0) ? 0.17677669529663687f : 1.0f;
      u16* bp = Qo + (size_t)(t * 8 + h) * PLANE + d;
      #pragma unroll
      for (int r = 0; r < 4; ++r) {
        const int row = m0 + wm * 64 + mt * 16 + kg * 4 + r;
        bp[(size_t)row * 64] = f2bf((acc[mt][nt][r] + bc) * sc);
      }
    }
  }
}

// ---------------- barrier-free attention: one wave per (window, head) ----------------
// v staged per-wave into LDS as vT[d][tok^swz] (stride 72) -> PV B-frags are b128 reads.
__global__ __launch_bounds__(256, 3) void attn3(
    const u16* __restrict__ qkv, const float* __restrict__ rpb,
    u16* __restrict__ concat, int wbase)
{
  __shared__ __align__(16) u16 sP[4][3136];    // per-wave P / out buffer (49 x 64, swizzled)
  __shared__ __align__(16) u16 sVT[4][4608];   // per-wave vT: [d][tok^((d>>3)&3)<<4], stride 72
  __shared__ float sRpb[4][169];

  const int tid = threadIdx.x;
  const int wv = tid >> 6, lane = tid & 63;
  const int rq = lane & 15, kg = lane >> 4;
  const int gw = blockIdx.x * 4 + wv;
  const int wl = gw >> 3, h = gw & 7;
  const int w = wbase + wl;
  const int win = w & 63, wh = win >> 3, ww = win & 7;
  const bool edge = (wh == 7) || (ww == 7);
  u16* sPw = sP[wv];
  u16* sVw = sVT[wv];

  for (int e = lane; e < 169; e += 64) sRpb[wv][e] = rpb[e * 8 + h];

  const u16* qbase = qkv + (size_t)h * PLANE + (size_t)wl * 49 * 64;
  const u16* kbase = qkv + KOFF + (size_t)h * PLANE + (size_t)wl * 49 * 64;
  const u16* vbase = qkv + VOFF + (size_t)h * PLANE + (size_t)wl * 49 * 64;

  // ---- issue v row loads early (hidden under QK^T) ----
  short8 vreg[4][2];
  #pragma unroll
  for (int t = 0; t < 4; ++t)
    #pragma unroll
    for (int h2 = 0; h2 < 2; ++h2)
      vreg[t][h2] = *(const short8*)(vbase + (size_t)(16 * t + rq) * 64 + kg * 8 + h2 * 32);

  // ---- K fragments (all), then S with per-i Q loads ----
  short8 ak[4][2];
  #pragma unroll
  for (int j = 0; j < 4; ++j) {
    const int rr = (16 * j + rq) > 48 ? 48 : (16 * j + rq);
    ak[j][0] = *(const short8*)(kbase + rr * 64 + kg * 8);
    ak[j][1] = *(const short8*)(kbase + rr * 64 + 32 + kg * 8);
  }
  f32x4 sacc[4][4];
  #pragma unroll
  for (int i = 0; i < 4; ++i)
    #pragma unroll
    for (int j = 0; j < 4; ++j) sacc[i][j] = f32x4{0,0,0,0};
  #pragma unroll
  for (int i = 0; i < 4; ++i) {
    const int rr = (16 * i + rq) > 48 ? 48 : (16 * i + rq);
    const short8 a0 = *(const short8*)(qbase + rr * 64 + kg * 8);
    const short8 a1 = *(const short8*)(qbase + rr * 64 + 32 + kg * 8);
    #pragma unroll
    for (int j = 0; j < 4; ++j) {
      sacc[i][j] = mfma16(a0, ak[j][0], sacc[i][j]);
      sacc[i][j] = mfma16(a1, ak[j][1], sacc[i][j]);
    }
  }

  // ---- write v into LDS vT (conflict-free: row ^ (kg<<4)) ----
  #pragma unroll
  for (int t = 0; t < 4; ++t) {
    const int row = 16 * t + rq;
    #pragma unroll
    for (int h2 = 0; h2 < 2; ++h2) {
      const int c0 = kg * 8 + h2 * 32;
      #pragma unroll
      for (int j = 0; j < 8; ++j)
        sVw[(c0 + j) * 72 + (row ^ (kg << 4))] = (u16)vreg[t][h2][j];
    }
  }

  // ---- bias + mask + softmax; P -> sPw (swizzled) ----
  #pragma unroll
  for (int i = 0; i < 4; ++i) {
    #pragma unroll
    for (int r = 0; r < 4; ++r) {
      const int n = 16 * i + kg * 4 + r;
      const bool nv = n < 49;
      const int r1 = n / 7, c1 = n - r1 * 7;
      int reg1 = 0;
      if (edge && nv) {
        const int sh1 = wh * 7 + r1, sw1 = ww * 7 + c1;
        reg1 = (sh1 < 49 ? 0 : (sh1 < 53 ? 1 : 2)) * 3 + (sw1 < 49 ? 0 : (sw1 < 53 ? 1 : 2));
      }
      float pv[4];
      #pragma unroll
      for (int j = 0; j < 4; ++j) {
        const int m = 16 * j + rq;
        float sv = -1e30f;
        if (nv && m < 49) {
          const int r2 = m / 7, c2 = m - r2 * 7;
          const int rel = (r1 - r2 + 6) * 13 + (c1 - c2 + 6);
          float msk = 0.f;
          if (edge) {
            const int sh2 = wh * 7 + r2, sw2 = ww * 7 + c2;
            const int reg2 = (sh2 < 49 ? 0 : (sh2 < 53 ? 1 : 2)) * 3 + (sw2 < 49 ? 0 : (sw2 < 53 ? 1 : 2));
            msk = (reg1 == reg2) ? 0.f : -100.f;
          }
          sv = sacc[i][j][r] + sRpb[wv][rel] + msk;
        }
        pv[j] = sv;
      }
      float mx = fmaxf(fmaxf(pv[0], pv[1]), fmaxf(pv[2], pv[3]));
      #pragma unroll
      for (int off = 1; off < 16; off <<= 1) mx = fmaxf(mx, __shfl_xor(mx, off));
      float sm = 0.f;
      #pragma unroll
      for (int j = 0; j < 4; ++j) { const float e = __expf(pv[j] - mx); pv[j] = e; sm += e; }
      #pragma unroll
      for (int off = 1; off < 16; off <<= 1) sm += __shfl_xor(sm, off);
      const float inv = 1.0f / sm;
      if (nv) {
        #pragma unroll
        for (int j = 0; j < 4; ++j) {
          const int col = 16 * j + rq;
          sPw[n * 64 + (((col >> 3) ^ (n & 7)) << 3) + (col & 7)] = f2bf(pv[j] * inv);
        }
      }
    }
  }

  // ---- PV: A = P (LDS), B = vT (LDS b128, pad toks masked) ----
  f32x4 oacc[4][4];
  #pragma unroll
  for (int i = 0; i < 4; ++i)
    #pragma unroll
    for (int j = 0; j < 4; ++j) oacc[i][j] = f32x4{0,0,0,0};
  #pragma unroll
  for (int m0v = 0; m0v < 2; ++m0v) {
    short8 av[4];
    #pragma unroll
    for (int ct = 0; ct < 4; ++ct) {
      const int col = ct * 16 + rq;
      const int s = (col >> 3) & 3;
      short8 vvv = *(const short8*)(sVw + col * 72 + ((m0v * 32 + kg * 8) ^ (s << 4)));
      if (m0v == 1) {
        if (kg == 3) {
          #pragma unroll
          for (int e = 0; e < 8; ++e) vvv[e] = 0;        // tokens 56..63: pad
        } else if (kg == 2) {
          #pragma unroll
          for (int e = 1; e < 8; ++e) vvv[e] = 0;        // tokens 49..55: pad
        }
      }
      av[ct] = vvv;
    }
    #pragma unroll
    for (int i = 0; i < 4; ++i) {
      const int rr = (16 * i + rq) > 48 ? 48 : (16 * i + rq);
      const int ch = (m0v * 4 + kg) ^ (rr & 7);
      const short8 pa = *(const short8*)(sPw + rr * 64 + ch * 8);
      #pragma unroll
      for (int ct = 0; ct < 4; ++ct)
        oacc[i][ct] = mfma16(pa, av[ct], oacc[i][ct]);
    }
  }

  // ---- repack out_h through LDS (reuse sPw), coalesced b128 store ----
  __builtin_amdgcn_s_waitcnt(0);  // wave-local LDS reuse: P reads done (single wave)
  #pragma unroll
  for (int i = 0; i < 4; ++i)
    #pragma unroll
    for (int ct = 0; ct < 4; ++ct)
      #pragma unroll
      for (int r = 0; r < 4; ++r) {
        const int n = 16 * i + kg * 4 + r;
        if (n < 49) {
          const int col = ct * 16 + rq;
          sPw[n * 64 + (((col >> 3) ^ (n & 7)) << 3) + (col & 7)] = f2bf(oacc[i][ct][r]);
        }
      }
  u16* crow = concat + (size_t)(wl * 49) * 512 + h * 64;
  #pragma unroll
  for (int it = 0; it < 7; ++it) {
    const int c = it * 64 + lane;
    if (c < 392) {
      const int m = c >> 3, s = c & 7;
      const short8 vvv = *(const short8*)(sPw + m * 64 + ((s ^ (m & 7)) << 3));
      *(short8*)(crow + (size_t)m * 512 + s * 8) = vvv;
    }
  }
}

// ---------------- proj GEMM + LN2 fused: BM=128, BN=256 (full row); grid 196 ----------------
__global__ __launch_bounds__(256, 2) void projln(
    const u16* __restrict__ A, const u16* __restrict__ Bw,
    const float* __restrict__ bias, const float* __restrict__ x,
    const float* __restrict__ g2, const float* __restrict__ b2,
    float* __restrict__ out, u16* __restrict__ xn2, int rowbase)
{
  __shared__ __align__(16) u16 sA[128 * 64];
  __shared__ __align__(16) u16 sB[256 * 64];
  const int m0 = blockIdx.x * 128;
  const int tid = threadIdx.x;
  const int lane = tid & 63;
  const int wv = tid >> 6;
  const int rq = lane & 15, kg = lane >> 4;
  f32x4 acc[2][16];
  #pragma unroll
  for (int i = 0; i < 2; ++i)
    #pragma unroll
    for (int j = 0; j < 16; ++j) acc[i][j] = f32x4{0,0,0,0};

  for (int kt = 0; kt < 8; ++kt) {
    if (kt) __syncthreads();
    #pragma unroll
    for (int i = 0; i < 4; ++i) {
      const int c = i * 256 + tid;
      gload16(A + (size_t)(m0 + (c >> 3)) * 512 + kt * 64 + (c & 7) * 8, sA + c * 8);
    }
    #pragma unroll
    for (int i = 0; i < 8; ++i) {
      const int c = i * 256 + tid;
      gload16(Bw + (size_t)(c >> 3) * 512 + kt * 64 + (c & 7) * 8, sB + c * 8);
    }
    __syncthreads();
    #pragma unroll
    for (int k0 = 0; k0 < 2; ++k0) {
      short8 af[2];
      #pragma unroll
      for (int mt = 0; mt < 2; ++mt)
        af[mt] = *(const short8*)(sA + (wv * 32 + mt * 16 + rq) * 64 + k0 * 32 + kg * 8);
      #pragma unroll
      for (int nt = 0; nt < 16; ++nt) {
        const short8 bf8 = *(const short8*)(sB + (nt * 16 + rq) * 64 + k0 * 32 + kg * 8);
        #pragma unroll
        for (int mt = 0; mt < 2; ++mt)
          acc[mt][nt] = mfma16(af[mt], bf8, acc[mt][nt]);
      }
    }
  }

  float br[16], g2r[16], b2r[16];
  #pragma unroll
  for (int nt = 0; nt < 16; ++nt) {
    const int col = nt * 16 + rq;
    br[nt] = bias[col]; g2r[nt] = g2[col]; b2r[nt] = b2[col];
  }
  #pragma unroll
  for (int mt = 0; mt < 2; ++mt) {
    #pragma unroll
    for (int r = 0; r < 4; ++r) {
      const int row = m0 + wv * 32 + mt * 16 + kg * 4 + r;
      const u32 g = (u32)(rowbase + row);
      const u32 w = g / 49u; const u32 n = g - w * 49u;
      const int b = w >> 6, win = w & 63, wh = win >> 3, ww = win & 7;
      const u32 rr = n / 7u; const u32 cc = n - rr * 7u;
      int oh = wh * 7 + (int)rr + 3; if (oh >= 56) oh -= 56;
      int ow = ww * 7 + (int)cc + 3; if (ow >= 56) ow -= 56;
      const size_t po = ((size_t)b * 3136 + oh * 56 + ow) * 256;
      float vals[16];
      float s = 0.f;
      #pragma unroll
      for (int nt = 0; nt < 16; ++nt) {
        const float v = acc[mt][nt][r] + br[nt] + x[po + nt * 16 + rq];
        vals[nt] = v; s += v;
      }
      #pragma unroll
      for (int off = 1; off < 16; off <<= 1) s += __shfl_xor(s, off);
      const float mean = s * (1.0f / 256.0f);
      float sq = 0.f;
      #pragma unroll
      for (int nt = 0; nt < 16; ++nt) { const float d_ = vals[nt] - mean; sq += d_ * d_; }
      #pragma unroll
      for (int off = 1; off < 16; off <<= 1) sq += __shfl_xor(sq, off);
      const float rstd = rsqrtf(sq * (1.0f / 256.0f) + 1e-5f);
      #pragma unroll
      for (int nt = 0; nt < 16; ++nt) {
        const int col = nt * 16 + rq;
        out[po + col] = vals[nt];
        xn2[po + col] = f2bf((vals[nt] - mean) * rstd * g2r[nt] + b2r[nt]);
      }
    }
  }
}

// ---------------- MLP GEMMs (128x128, XCD-swizzled) ----------------
template<int K, int NOUT, bool GELU>
__global__ __launch_bounds__(256) void mlp_gemm(
    const u16* __restrict__ A, const u16* __restrict__ Bw,
    const float* __restrict__ bias, u16* __restrict__ obf, float* __restrict__ ofr)
{
  __shared__ __align__(16) u16 sA[128 * 64];
  __shared__ __align__(16) u16 sB[128 * 64];
  const int nx = gridDim.x;
  const int nwg = nx * gridDim.y;
  const int orig = blockIdx.y * nx + blockIdx.x;
  const int sw = (orig & 7) * (nwg >> 3) + (orig >> 3);
  const int m0  = (sw / nx) * 128;
  const int nn0 = (sw % nx) * 128;
  const int tid = threadIdx.x;
  const int lane = tid & 63;
  const int wv = tid >> 6;
  const int wm = wv >> 1, wn = wv & 1;
  const int rq = lane & 15, kg = lane >> 4;
  f32x4 acc[4][4];
  #pragma unroll
  for (int i = 0; i < 4; ++i)
    #pragma unroll
    for (int j = 0; j < 4; ++j) acc[i][j] = f32x4{0,0,0,0};

  for (int kt = 0; kt < K / 64; ++kt) {
    if (kt) __syncthreads();
    #pragma unroll
    for (int i = 0; i < 4; ++i) {
      const int c = i * 256 + tid;
      gload16(A + (size_t)(m0 + (c >> 3)) * K + kt * 64 + (c & 7) * 8, sA + c * 8);
    }
    #pragma unroll
    for (int i = 0; i < 4; ++i) {
      const int c = i * 256 + tid;
      gload16(Bw + (size_t)(nn0 + (c >> 3)) * K + kt * 64 + (c & 7) * 8, sB + c * 8);
    }
    __syncthreads();
    #pragma unroll
    for (int k0 = 0; k0 < 2; ++k0) {
      short8 af[4], bf8[4];
      #pragma unroll
      for (int mt = 0; mt < 4; ++mt)
        af[mt] = *(const short8*)(sA + (wm * 64 + mt * 16 + rq) * 64 + k0 * 32 + kg * 8);
      #pragma unroll
      for (int nt = 0; nt < 4; ++nt)
        bf8[nt] = *(const short8*)(sB + (wn * 64 + nt * 16 + rq) * 64 + k0 * 32 + kg * 8);
      #pragma unroll
      for (int mt = 0; mt < 4; ++mt)
        #pragma unroll
        for (int nt = 0; nt < 4; ++nt)
          acc[mt][nt] = mfma16(af[mt], bf8[nt], acc[mt][nt]);
    }
  }
  #pragma unroll
  for (int mt = 0; mt < 4; ++mt) {
    #pragma unroll
    for (int nt = 0; nt < 4; ++nt) {
      const int col = nn0 + wn * 64 + nt * 16 + rq;
      const float bcol = bias[col];
      #pragma unroll
      for (int r = 0; r < 4; ++r) {
        const int row = m0 + wm * 64 + mt * 16 + kg * 4 + r;
        float v = acc[mt][nt][r] + bcol;
        if constexpr (GELU) {
          v = 0.5f * v * (1.0f + erff(v * 0.7071067811865476f));
          obf[(size_t)row * NOUT + col] = f2bf(v);
        } else {
          float* p = ofr + (size_t)row * NOUT + col;
          *p = v + *p;
        }
      }
    }
  }
}

extern "C" void kernel_launch(void* const* d_in, const int* in_sizes, int n_in,
                              void* d_out, int out_size, void* d_ws, size_t ws_size,
                              hipStream_t stream) {
  const float* x      = (const float*)d_in[0];
  const float* y      = (const float*)d_in[1];
  const float* g1     = (const float*)d_in[2];
  const float* b1     = (const float*)d_in[3];
  const float* rpb    = (const float*)d_in[4];
  const float* w_qkv  = (const float*)d_in[5];
  const float* b_qkv  = (const float*)d_in[6];
  const float* w_proj = (const float*)d_in[7];
  const float* b_proj = (const float*)d_in[8];
  const float* g2     = (const float*)d_in[9];
  const float* b2     = (const float*)d_in[10];
  const float* w_fc1  = (const float*)d_in[11];
  const float* b_fc1  = (const float*)d_in[12];
  const float* w_fc2  = (const float*)d_in[13];
  const float* b_fc2  = (const float*)d_in[14];
  float* out = (float*)d_out;

  u16* wsp = (u16*)d_ws;
  u16* wqkv_bf  = wsp;                       //  786432
  u16* wproj_bf = wsp + 786432;              //  131072
  u16* wfc1_bf  = wsp + 917504;              //  262144
  u16* wfc2_bf  = wsp + 1179648;             //  262144
  u16* xn2      = wsp + 1441792;             //  25690112
  u16* XYc      = wsp + 27131904;            //  12845056 (25088 x 512) XY, then concat
  u16* qkvc     = wsp + 39976960;            //  24 planes x 25088 x 64 (+ slack)
  u16* hbuf     = XYc;                       //  overlay (dead in MLP phase)

  convk<<<768, 256, 0, stream>>>(w_qkv,  wqkv_bf,  196608);
  convk<<<128, 256, 0, stream>>>(w_proj, wproj_bf, 32768);
  convk<<<256, 256, 0, stream>>>(w_fc1,  wfc1_bf,  65536);
  convk<<<256, 256, 0, stream>>>(w_fc2,  wfc2_bf,  65536);

  for (int c = 0; c < 4; ++c) {
    ln_gather<<<6272, 256, 0, stream>>>(x, y, g1, b1, XYc, c * CHUNK_ROWS);
    qkv_gemm<<<dim3(12, 196), 256, 0, stream>>>(XYc, wqkv_bf, b_qkv, qkvc);
    attn3<<<1024, 256, 0, stream>>>(qkvc, rpb, XYc, c * 512);
    projln<<<196, 256, 0, stream>>>(XYc, wproj_bf, b_proj, x, g2, b2, out, xn2, c * CHUNK_ROWS);
  }

  for (int c = 0; c < 4; ++c) {
    mlp_gemm<256, 1024, true><<<dim3(8, 196), 256, 0, stream>>>(
        xn2 + (size_t)c * CHUNK_ROWS * 256, wfc1_bf, b_fc1, hbuf, nullptr);
    mlp_gemm<1024, 256, false><<<dim3(2, 196), 256, 0, stream>>>(
        hbuf, wfc2_bf, b_fc2, nullptr, out + (size_t)c * CHUNK_ROWS * 256);
  }
}

// Round 7
// 964.585 us; speedup vs baseline: 1.2462x; 1.1417x over previous
//
#include <hip/hip_runtime.h>
#include <hip/hip_bf16.h>

#define DEVI __device__ __forceinline__

typedef __attribute__((ext_vector_type(8))) short short8;
typedef __attribute__((ext_vector_type(4))) float f32x4;
typedef unsigned int u32;
typedef unsigned short u16;

typedef __attribute__((address_space(1))) const u32 gu32_t;
typedef __attribute__((address_space(3))) u32 lu32_t;

DEVI u16 f2bf(float f) {
  u32 u = __builtin_bit_cast(u32, f);
  u32 r = (u + 0x7fffu + ((u >> 16) & 1u)) >> 16;
  return (u16)r;
}

DEVI f32x4 mfma16(short8 a, short8 b, f32x4 c) {
  return __builtin_amdgcn_mfma_f32_16x16x32_bf16(a, b, c, 0, 0, 0);
}

DEVI void gload16(const void* g, void* l) {
  __builtin_amdgcn_global_load_lds((gu32_t*)g, (lu32_t*)l, 16, 0, 0);
}

#define CHUNK_ROWS 25088   // 512 windows * 49 tokens
#define PLANE ((size_t)CHUNK_ROWS * 64)
#define KOFF  ((size_t)8 * PLANE)          // k planes base
#define VOFF  ((size_t)16 * PLANE)         // v planes base (linear)

// ---------------- weight f32 -> bf16 ----------------
__global__ __launch_bounds__(256) void convk(const float* __restrict__ s, u16* __restrict__ d, int n4) {
  int i = blockIdx.x * 256 + threadIdx.x;
  if (i < n4) {
    const float4 v = ((const float4*)s)[i];
    ushort4 o;
    o.x = f2bf(v.x); o.y = f2bf(v.y); o.z = f2bf(v.z); o.w = f2bf(v.w);
    ((ushort4*)d)[i] = o;
  }
}

// ---------------- fused bias+mask+pad table: [4 cls][8 h][64 n][64 m] f32 ----------------
__global__ __launch_bounds__(256) void btab_build(const float* __restrict__ rpb, float* __restrict__ btab) {
  const int cls = blockIdx.x >> 3, h = blockIdx.x & 7;
  float* dst = btab + (size_t)(cls * 8 + h) * 4096;
  for (int e = threadIdx.x; e < 4096; e += 256) {
    const int n = e >> 6, m = e & 63;
    float v;
    if (m >= 49) {
      v = -1e30f;                    // pad columns: exp -> 0
    } else if (n >= 49) {
      v = 0.f;                       // pad rows: benign (writes guarded)
    } else {
      const int r1 = n / 7, c1 = n - r1 * 7;
      const int r2 = m / 7, c2 = m - r2 * 7;
      const int rel = (r1 - r2 + 6) * 13 + (c1 - c2 + 6);
      v = rpb[rel * 8 + h];
      const int reg1 = ((cls & 1) ? (r1 < 4 ? 1 : 2) : 0) * 3 + ((cls & 2) ? (c1 < 4 ? 1 : 2) : 0);
      const int reg2 = ((cls & 1) ? (r2 < 4 ? 1 : 2) : 0) * 3 + ((cls & 2) ? (c2 < 4 ? 1 : 2) : 0);
      if (reg1 != reg2) v -= 100.f;
    }
    dst[e] = v;
  }
}

// ---------------- LN1 + shift + window gather -> XY bf16 [CHUNK_ROWS][512] ----------------
__global__ __launch_bounds__(256) void ln_gather(
    const float* __restrict__ x, const float* __restrict__ y,
    const float* __restrict__ g1, const float* __restrict__ b1,
    u16* __restrict__ XY, int rowbase)
{
  const int wv = threadIdx.x >> 6, lane = threadIdx.x & 63;
  const int rl = blockIdx.x * 4 + wv;
  const int row = rowbase + rl;
  const int w = row / 49, n = row - w * 49;
  const int b = w >> 6, win = w & 63, wh = win >> 3, ww = win & 7;
  const int r = n / 7, c = n - r * 7;
  int oh = wh * 7 + r + 3; if (oh >= 56) oh -= 56;
  int ow = ww * 7 + c + 3; if (ow >= 56) ow -= 56;
  const size_t po = ((size_t)b * 3136 + oh * 56 + ow) * 256;
  const float4 g1v = ((const float4*)g1)[lane];
  const float4 b1v = ((const float4*)b1)[lane];
  u16* orow = XY + (size_t)rl * 512;
  #pragma unroll
  for (int mod = 0; mod < 2; ++mod) {
    const float* src = (mod ? y : x) + po;
    const float4 v = ((const float4*)src)[lane];
    float s = v.x + v.y + v.z + v.w;
    #pragma unroll
    for (int off = 1; off < 64; off <<= 1) s += __shfl_xor(s, off);
    const float mean = s * (1.0f / 256.0f);
    const float d0 = v.x - mean, d1 = v.y - mean, d2 = v.z - mean, d3 = v.w - mean;
    float sq = d0 * d0 + d1 * d1 + d2 * d2 + d3 * d3;
    #pragma unroll
    for (int off = 1; off < 64; off <<= 1) sq += __shfl_xor(sq, off);
    const float rstd = rsqrtf(sq * (1.0f / 256.0f) + 1e-5f);
    ushort4 o;
    o.x = f2bf(d0 * rstd * g1v.x + b1v.x);
    o.y = f2bf(d1 * rstd * g1v.y + b1v.y);
    o.z = f2bf(d2 * rstd * g1v.z + b1v.z);
    o.w = f2bf(d3 * rstd * g1v.w + b1v.w);
    *(ushort4*)(orow + mod * 256 + lane * 4) = o;
  }
}

// ---------------- QKV GEMM (128x128, XCD-swizzled): M=25088, N=1536, K=512 ----------------
__global__ __launch_bounds__(256) void qkv_gemm(
    const u16* __restrict__ A, const u16* __restrict__ Bw,
    const float* __restrict__ bias, u16* __restrict__ Qo)
{
  __shared__ __align__(16) u16 sA[128 * 64];
  __shared__ __align__(16) u16 sB[128 * 64];
  const int nx = gridDim.x;
  const int nwg = nx * gridDim.y;
  const int orig = blockIdx.y * nx + blockIdx.x;
  const int sw = (orig & 7) * (nwg >> 3) + (orig >> 3);
  const int m0  = (sw / nx) * 128;
  const int nn0 = (sw % nx) * 128;
  const int tid = threadIdx.x;
  const int lane = tid & 63;
  const int wv = tid >> 6;
  const int wm = wv >> 1, wn = wv & 1;
  const int rq = lane & 15, kg = lane >> 4;
  f32x4 acc[4][4];
  #pragma unroll
  for (int i = 0; i < 4; ++i)
    #pragma unroll
    for (int j = 0; j < 4; ++j) acc[i][j] = f32x4{0,0,0,0};

  for (int kt = 0; kt < 8; ++kt) {
    if (kt) __syncthreads();
    #pragma unroll
    for (int i = 0; i < 4; ++i) {
      const int c = i * 256 + tid;
      gload16(A + (size_t)(m0 + (c >> 3)) * 512 + kt * 64 + (c & 7) * 8, sA + c * 8);
    }
    #pragma unroll
    for (int i = 0; i < 4; ++i) {
      const int c = i * 256 + tid;
      gload16(Bw + (size_t)(nn0 + (c >> 3)) * 512 + kt * 64 + (c & 7) * 8, sB + c * 8);
    }
    __syncthreads();
    #pragma unroll
    for (int k0 = 0; k0 < 2; ++k0) {
      short8 af[4], bf8[4];
      #pragma unroll
      for (int mt = 0; mt < 4; ++mt)
        af[mt] = *(const short8*)(sA + (wm * 64 + mt * 16 + rq) * 64 + k0 * 32 + kg * 8);
      #pragma unroll
      for (int nt = 0; nt < 4; ++nt)
        bf8[nt] = *(const short8*)(sB + (wn * 64 + nt * 16 + rq) * 64 + k0 * 32 + kg * 8);
      #pragma unroll
      for (int mt = 0; mt < 4; ++mt)
        #pragma unroll
        for (int nt = 0; nt < 4; ++nt)
          acc[mt][nt] = mfma16(af[mt], bf8[nt], acc[mt][nt]);
    }
  }
  #pragma unroll
  for (int mt = 0; mt < 4; ++mt) {
    #pragma unroll
    for (int nt = 0; nt < 4; ++nt) {
      const int col = nn0 + wn * 64 + nt * 16 + rq;
      const int t = col >> 9, rem = col & 511;
      const int h = rem >> 6, d = rem & 63;
      const float bc = bias[col];
      const float sc = (t == 0) ? 0.17677669529663687f : 1.0f;
      u16* bp = Qo + (size_t)(t * 8 + h) * PLANE + d;
      #pragma unroll
      for (int r = 0; r < 4; ++r) {
        const int row = m0 + wm * 64 + mt * 16 + kg * 4 + r;
        bp[(size_t)row * 64] = f2bf((acc[mt][nt][r] + bc) * sc);
      }
    }
  }
}

// ---------------- barrier-free attention: one wave per (window, head), table-driven softmax ----------------
__global__ __launch_bounds__(256, 3) void attn3(
    const u16* __restrict__ qkv, const float* __restrict__ btab,
    u16* __restrict__ concat, int wbase)
{
  __shared__ __align__(16) u16 sP[4][3136];    // per-wave P / out buffer (49 x 64, swizzled)
  __shared__ __align__(16) u16 sVT[4][4608];   // per-wave vT: [d][tok^((d>>3)&3)<<4], stride 72

  const int tid = threadIdx.x;
  const int wv = tid >> 6, lane = tid & 63;
  const int rq = lane & 15, kg = lane >> 4;
  const int gw = blockIdx.x * 4 + wv;
  const int wl = gw >> 3, h = gw & 7;
  const int w = wbase + wl;
  const int win = w & 63, wh = win >> 3, ww = win & 7;
  const int cls = ((wh == 7) ? 1 : 0) | ((ww == 7) ? 2 : 0);
  const float* Tb = btab + (size_t)(cls * 8 + h) * 4096;
  u16* sPw = sP[wv];
  u16* sVw = sVT[wv];

  const u16* qbase = qkv + (size_t)h * PLANE + (size_t)wl * 49 * 64;
  const u16* kbase = qkv + KOFF + (size_t)h * PLANE + (size_t)wl * 49 * 64;
  const u16* vbase = qkv + VOFF + (size_t)h * PLANE + (size_t)wl * 49 * 64;

  // ---- issue v row loads early (hidden under QK^T) ----
  short8 vreg[4][2];
  #pragma unroll
  for (int t = 0; t < 4; ++t)
    #pragma unroll
    for (int h2 = 0; h2 < 2; ++h2)
      vreg[t][h2] = *(const short8*)(vbase + (size_t)(16 * t + rq) * 64 + kg * 8 + h2 * 32);

  // ---- K fragments (all), then S with per-i Q loads ----
  short8 ak[4][2];
  #pragma unroll
  for (int j = 0; j < 4; ++j) {
    const int rr = (16 * j + rq) > 48 ? 48 : (16 * j + rq);
    ak[j][0] = *(const short8*)(kbase + rr * 64 + kg * 8);
    ak[j][1] = *(const short8*)(kbase + rr * 64 + 32 + kg * 8);
  }
  f32x4 sacc[4][4];
  #pragma unroll
  for (int i = 0; i < 4; ++i)
    #pragma unroll
    for (int j = 0; j < 4; ++j) sacc[i][j] = f32x4{0,0,0,0};
  #pragma unroll
  for (int i = 0; i < 4; ++i) {
    const int rr = (16 * i + rq) > 48 ? 48 : (16 * i + rq);
    const short8 a0 = *(const short8*)(qbase + rr * 64 + kg * 8);
    const short8 a1 = *(const short8*)(qbase + rr * 64 + 32 + kg * 8);
    #pragma unroll
    for (int j = 0; j < 4; ++j) {
      sacc[i][j] = mfma16(a0, ak[j][0], sacc[i][j]);
      sacc[i][j] = mfma16(a1, ak[j][1], sacc[i][j]);
    }
  }

  // ---- write v into LDS vT (conflict-free: row ^ (kg<<4)) ----
  #pragma unroll
  for (int t = 0; t < 4; ++t) {
    const int row = 16 * t + rq;
    #pragma unroll
    for (int h2 = 0; h2 < 2; ++h2) {
      const int c0 = kg * 8 + h2 * 32;
      #pragma unroll
      for (int j = 0; j < 8; ++j)
        sVw[(c0 + j) * 72 + (row ^ (kg << 4))] = (u16)vreg[t][h2][j];
    }
  }

  // ---- table-driven softmax; P -> sPw (swizzled) ----
  #pragma unroll
  for (int i = 0; i < 4; ++i) {
    #pragma unroll
    for (int r = 0; r < 4; ++r) {
      const int n = 16 * i + kg * 4 + r;
      const float* Trow = Tb + n * 64 + rq;
      float pv[4];
      #pragma unroll
      for (int j = 0; j < 4; ++j)
        pv[j] = sacc[i][j][r] + Trow[16 * j];
      float mx = fmaxf(fmaxf(pv[0], pv[1]), fmaxf(pv[2], pv[3]));
      #pragma unroll
      for (int off = 1; off < 16; off <<= 1) mx = fmaxf(mx, __shfl_xor(mx, off));
      float sm = 0.f;
      #pragma unroll
      for (int j = 0; j < 4; ++j) { const float e = __expf(pv[j] - mx); pv[j] = e; sm += e; }
      #pragma unroll
      for (int off = 1; off < 16; off <<= 1) sm += __shfl_xor(sm, off);
      const float inv = 1.0f / sm;
      if (n < 49) {
        #pragma unroll
        for (int j = 0; j < 4; ++j) {
          const int col = 16 * j + rq;
          sPw[n * 64 + (((col >> 3) ^ (n & 7)) << 3) + (col & 7)] = f2bf(pv[j] * inv);
        }
      }
    }
  }

  // ---- PV: A = P (LDS), B = vT (LDS b128, pad toks masked) ----
  f32x4 oacc[4][4];
  #pragma unroll
  for (int i = 0; i < 4; ++i)
    #pragma unroll
    for (int j = 0; j < 4; ++j) oacc[i][j] = f32x4{0,0,0,0};
  #pragma unroll
  for (int m0v = 0; m0v < 2; ++m0v) {
    short8 av[4];
    #pragma unroll
    for (int ct = 0; ct < 4; ++ct) {
      const int col = ct * 16 + rq;
      const int s = (col >> 3) & 3;
      short8 vvv = *(const short8*)(sVw + col * 72 + ((m0v * 32 + kg * 8) ^ (s << 4)));
      if (m0v == 1) {
        if (kg == 3) {
          #pragma unroll
          for (int e = 0; e < 8; ++e) vvv[e] = 0;        // tokens 56..63: pad
        } else if (kg == 2) {
          #pragma unroll
          for (int e = 1; e < 8; ++e) vvv[e] = 0;        // tokens 49..55: pad
        }
      }
      av[ct] = vvv;
    }
    #pragma unroll
    for (int i = 0; i < 4; ++i) {
      const int rr = (16 * i + rq) > 48 ? 48 : (16 * i + rq);
      const int ch = (m0v * 4 + kg) ^ (rr & 7);
      const short8 pa = *(const short8*)(sPw + rr * 64 + ch * 8);
      #pragma unroll
      for (int ct = 0; ct < 4; ++ct)
        oacc[i][ct] = mfma16(pa, av[ct], oacc[i][ct]);
    }
  }

  // ---- repack out_h through LDS (reuse sPw), coalesced b128 store ----
  __builtin_amdgcn_s_waitcnt(0);  // wave-local LDS reuse: P reads done (single wave)
  #pragma unroll
  for (int i = 0; i < 4; ++i)
    #pragma unroll
    for (int ct = 0; ct < 4; ++ct)
      #pragma unroll
      for (int r = 0; r < 4; ++r) {
        const int n = 16 * i + kg * 4 + r;
        if (n < 49) {
          const int col = ct * 16 + rq;
          sPw[n * 64 + (((col >> 3) ^ (n & 7)) << 3) + (col & 7)] = f2bf(oacc[i][ct][r]);
        }
      }
  u16* crow = concat + (size_t)(wl * 49) * 512 + h * 64;
  #pragma unroll
  for (int it = 0; it < 7; ++it) {
    const int c = it * 64 + lane;
    if (c < 392) {
      const int m = c >> 3, s = c & 7;
      const short8 vvv = *(const short8*)(sPw + m * 64 + ((s ^ (m & 7)) << 3));
      *(short8*)(crow + (size_t)m * 512 + s * 8) = vvv;
    }
  }
}

// ---------------- proj GEMM + LN2 fused: BM=128, BN=256 (full row); grid 196 ----------------
__global__ __launch_bounds__(256, 2) void projln(
    const u16* __restrict__ A, const u16* __restrict__ Bw,
    const float* __restrict__ bias, const float* __restrict__ x,
    const float* __restrict__ g2, const float* __restrict__ b2,
    float* __restrict__ out, u16* __restrict__ xn2, int rowbase)
{
  __shared__ __align__(16) u16 sA[128 * 64];
  __shared__ __align__(16) u16 sB[256 * 64];
  const int m0 = blockIdx.x * 128;
  const int tid = threadIdx.x;
  const int lane = tid & 63;
  const int wv = tid >> 6;
  const int rq = lane & 15, kg = lane >> 4;
  f32x4 acc[2][16];
  #pragma unroll
  for (int i = 0; i < 2; ++i)
    #pragma unroll
    for (int j = 0; j < 16; ++j) acc[i][j] = f32x4{0,0,0,0};

  for (int kt = 0; kt < 8; ++kt) {
    if (kt) __syncthreads();
    #pragma unroll
    for (int i = 0; i < 4; ++i) {
      const int c = i * 256 + tid;
      gload16(A + (size_t)(m0 + (c >> 3)) * 512 + kt * 64 + (c & 7) * 8, sA + c * 8);
    }
    #pragma unroll
    for (int i = 0; i < 8; ++i) {
      const int c = i * 256 + tid;
      gload16(Bw + (size_t)(c >> 3) * 512 + kt * 64 + (c & 7) * 8, sB + c * 8);
    }
    __syncthreads();
    #pragma unroll
    for (int k0 = 0; k0 < 2; ++k0) {
      short8 af[2];
      #pragma unroll
      for (int mt = 0; mt < 2; ++mt)
        af[mt] = *(const short8*)(sA + (wv * 32 + mt * 16 + rq) * 64 + k0 * 32 + kg * 8);
      #pragma unroll
      for (int nt = 0; nt < 16; ++nt) {
        const short8 bf8 = *(const short8*)(sB + (nt * 16 + rq) * 64 + k0 * 32 + kg * 8);
        #pragma unroll
        for (int mt = 0; mt < 2; ++mt)
          acc[mt][nt] = mfma16(af[mt], bf8, acc[mt][nt]);
      }
    }
  }

  float br[16], g2r[16], b2r[16];
  #pragma unroll
  for (int nt = 0; nt < 16; ++nt) {
    const int col = nt * 16 + rq;
    br[nt] = bias[col]; g2r[nt] = g2[col]; b2r[nt] = b2[col];
  }
  #pragma unroll
  for (int mt = 0; mt < 2; ++mt) {
    #pragma unroll
    for (int r = 0; r < 4; ++r) {
      const int row = m0 + wv * 32 + mt * 16 + kg * 4 + r;
      const u32 g = (u32)(rowbase + row);
      const u32 w = g / 49u; const u32 n = g - w * 49u;
      const int b = w >> 6, win = w & 63, wh = win >> 3, ww = win & 7;
      const u32 rr = n / 7u; const u32 cc = n - rr * 7u;
      int oh = wh * 7 + (int)rr + 3; if (oh >= 56) oh -= 56;
      int ow = ww * 7 + (int)cc + 3; if (ow >= 56) ow -= 56;
      const size_t po = ((size_t)b * 3136 + oh * 56 + ow) * 256;
      float vals[16];
      float s = 0.f;
      #pragma unroll
      for (int nt = 0; nt < 16; ++nt) {
        const float v = acc[mt][nt][r] + br[nt] + x[po + nt * 16 + rq];
        vals[nt] = v; s += v;
      }
      #pragma unroll
      for (int off = 1; off < 16; off <<= 1) s += __shfl_xor(s, off);
      const float mean = s * (1.0f / 256.0f);
      float sq = 0.f;
      #pragma unroll
      for (int nt = 0; nt < 16; ++nt) { const float d_ = vals[nt] - mean; sq += d_ * d_; }
      #pragma unroll
      for (int off = 1; off < 16; off <<= 1) sq += __shfl_xor(sq, off);
      const float rstd = rsqrtf(sq * (1.0f / 256.0f) + 1e-5f);
      #pragma unroll
      for (int nt = 0; nt < 16; ++nt) {
        const int col = nt * 16 + rq;
        out[po + col] = vals[nt];
        xn2[po + col] = f2bf((vals[nt] - mean) * rstd * g2r[nt] + b2r[nt]);
      }
    }
  }
}

// ---------------- MLP GEMMs (128x128, XCD-swizzled) ----------------
template<int K, int NOUT, bool GELU>
__global__ __launch_bounds__(256) void mlp_gemm(
    const u16* __restrict__ A, const u16* __restrict__ Bw,
    const float* __restrict__ bias, u16* __restrict__ obf, float* __restrict__ ofr)
{
  __shared__ __align__(16) u16 sA[128 * 64];
  __shared__ __align__(16) u16 sB[128 * 64];
  const int nx = gridDim.x;
  const int nwg = nx * gridDim.y;
  const int orig = blockIdx.y * nx + blockIdx.x;
  const int sw = (orig & 7) * (nwg >> 3) + (orig >> 3);
  const int m0  = (sw / nx) * 128;
  const int nn0 = (sw % nx) * 128;
  const int tid = threadIdx.x;
  const int lane = tid & 63;
  const int wv = tid >> 6;
  const int wm = wv >> 1, wn = wv & 1;
  const int rq = lane & 15, kg = lane >> 4;
  f32x4 acc[4][4];
  #pragma unroll
  for (int i = 0; i < 4; ++i)
    #pragma unroll
    for (int j = 0; j < 4; ++j) acc[i][j] = f32x4{0,0,0,0};

  for (int kt = 0; kt < K / 64; ++kt) {
    if (kt) __syncthreads();
    #pragma unroll
    for (int i = 0; i < 4; ++i) {
      const int c = i * 256 + tid;
      gload16(A + (size_t)(m0 + (c >> 3)) * K + kt * 64 + (c & 7) * 8, sA + c * 8);
    }
    #pragma unroll
    for (int i = 0; i < 4; ++i) {
      const int c = i * 256 + tid;
      gload16(Bw + (size_t)(nn0 + (c >> 3)) * K + kt * 64 + (c & 7) * 8, sB + c * 8);
    }
    __syncthreads();
    #pragma unroll
    for (int k0 = 0; k0 < 2; ++k0) {
      short8 af[4], bf8[4];
      #pragma unroll
      for (int mt = 0; mt < 4; ++mt)
        af[mt] = *(const short8*)(sA + (wm * 64 + mt * 16 + rq) * 64 + k0 * 32 + kg * 8);
      #pragma unroll
      for (int nt = 0; nt < 4; ++nt)
        bf8[nt] = *(const short8*)(sB + (wn * 64 + nt * 16 + rq) * 64 + k0 * 32 + kg * 8);
      #pragma unroll
      for (int mt = 0; mt < 4; ++mt)
        #pragma unroll
        for (int nt = 0; nt < 4; ++nt)
          acc[mt][nt] = mfma16(af[mt], bf8[nt], acc[mt][nt]);
    }
  }
  #pragma unroll
  for (int mt = 0; mt < 4; ++mt) {
    #pragma unroll
    for (int nt = 0; nt < 4; ++nt) {
      const int col = nn0 + wn * 64 + nt * 16 + rq;
      const float bcol = bias[col];
      #pragma unroll
      for (int r = 0; r < 4; ++r) {
        const int row = m0 + wm * 64 + mt * 16 + kg * 4 + r;
        float v = acc[mt][nt][r] + bcol;
        if constexpr (GELU) {
          v = 0.5f * v * (1.0f + erff(v * 0.7071067811865476f));
          obf[(size_t)row * NOUT + col] = f2bf(v);
        } else {
          float* p = ofr + (size_t)row * NOUT + col;
          *p = v + *p;
        }
      }
    }
  }
}

extern "C" void kernel_launch(void* const* d_in, const int* in_sizes, int n_in,
                              void* d_out, int out_size, void* d_ws, size_t ws_size,
                              hipStream_t stream) {
  const float* x      = (const float*)d_in[0];
  const float* y      = (const float*)d_in[1];
  const float* g1     = (const float*)d_in[2];
  const float* b1     = (const float*)d_in[3];
  const float* rpb    = (const float*)d_in[4];
  const float* w_qkv  = (const float*)d_in[5];
  const float* b_qkv  = (const float*)d_in[6];
  const float* w_proj = (const float*)d_in[7];
  const float* b_proj = (const float*)d_in[8];
  const float* g2     = (const float*)d_in[9];
  const float* b2     = (const float*)d_in[10];
  const float* w_fc1  = (const float*)d_in[11];
  const float* b_fc1  = (const float*)d_in[12];
  const float* w_fc2  = (const float*)d_in[13];
  const float* b_fc2  = (const float*)d_in[14];
  float* out = (float*)d_out;

  u16* wsp = (u16*)d_ws;
  u16* wqkv_bf  = wsp;                       //  786432
  u16* wproj_bf = wsp + 786432;              //  131072
  u16* wfc1_bf  = wsp + 917504;              //  262144
  u16* wfc2_bf  = wsp + 1179648;             //  262144
  float* btab   = (float*)(wsp + 1441792);   //  131072 f32 = 262144 u16
  u16* xn2      = wsp + 1703936;             //  25690112
  u16* XYc      = wsp + 27394048;            //  12845056 (25088 x 512) XY, then concat
  u16* qkvc     = wsp + 40239104;            //  24 planes x 25088 x 64
  u16* hbuf     = XYc;                       //  MLP overlay: 50176x1024 spans XYc+qkvc (dead)

  convk<<<768, 256, 0, stream>>>(w_qkv,  wqkv_bf,  196608);
  convk<<<128, 256, 0, stream>>>(w_proj, wproj_bf, 32768);
  convk<<<256, 256, 0, stream>>>(w_fc1,  wfc1_bf,  65536);
  convk<<<256, 256, 0, stream>>>(w_fc2,  wfc2_bf,  65536);
  btab_build<<<32, 256, 0, stream>>>(rpb, btab);

  for (int c = 0; c < 4; ++c) {
    ln_gather<<<6272, 256, 0, stream>>>(x, y, g1, b1, XYc, c * CHUNK_ROWS);
    qkv_gemm<<<dim3(12, 196), 256, 0, stream>>>(XYc, wqkv_bf, b_qkv, qkvc);
    attn3<<<1024, 256, 0, stream>>>(qkvc, btab, XYc, c * 512);
    projln<<<196, 256, 0, stream>>>(XYc, wproj_bf, b_proj, x, g2, b2, out, xn2, c * CHUNK_ROWS);
  }

  for (int c = 0; c < 2; ++c) {
    mlp_gemm<256, 1024, true><<<dim3(8, 392), 256, 0, stream>>>(
        xn2 + (size_t)c * 50176 * 256, wfc1_bf, b_fc1, hbuf, nullptr);
    mlp_gemm<1024, 256, false><<<dim3(2, 392), 256, 0, stream>>>(
        hbuf, wfc2_bf, b_fc2, nullptr, out + (size_t)c * 50176 * 256);
  }
}

// Round 8
// 866.240 us; speedup vs baseline: 1.3877x; 1.1135x over previous
//
#include <hip/hip_runtime.h>
#include <hip/hip_bf16.h>

#define DEVI __device__ __forceinline__

typedef __attribute__((ext_vector_type(8))) short short8;
typedef __attribute__((ext_vector_type(4))) float f32x4;
typedef unsigned int u32;
typedef unsigned short u16;

typedef __attribute__((address_space(1))) const u32 gu32_t;
typedef __attribute__((address_space(3))) u32 lu32_t;

DEVI u16 f2bf(float f) {
  u32 u = __builtin_bit_cast(u32, f);
  u32 r = (u + 0x7fffu + ((u >> 16) & 1u)) >> 16;
  return (u16)r;
}

DEVI f32x4 mfma16(short8 a, short8 b, f32x4 c) {
  return __builtin_amdgcn_mfma_f32_16x16x32_bf16(a, b, c, 0, 0, 0);
}

DEVI void gload16(const void* g, void* l) {
  __builtin_amdgcn_global_load_lds((gu32_t*)g, (lu32_t*)l, 16, 0, 0);
}

DEVI float gelu_t(float v) {
  const float u = v * (0.7978845608f + 0.0356774081f * v * v);
  const float t = 1.0f - 2.0f / (__expf(2.0f * u) + 1.0f);
  return 0.5f * v * (1.0f + t);
}

#define CHUNK_ROWS 25088   // 512 windows * 49 tokens
#define PLANE ((size_t)CHUNK_ROWS * 64)
#define KOFF  ((size_t)8 * PLANE)          // k planes base
#define VOFF  ((size_t)16 * PLANE)         // v planes base (linear)

// ---------------- weight f32 -> bf16 ----------------
__global__ __launch_bounds__(256) void convk(const float* __restrict__ s, u16* __restrict__ d, int n4) {
  int i = blockIdx.x * 256 + threadIdx.x;
  if (i < n4) {
    const float4 v = ((const float4*)s)[i];
    ushort4 o;
    o.x = f2bf(v.x); o.y = f2bf(v.y); o.z = f2bf(v.z); o.w = f2bf(v.w);
    ((ushort4*)d)[i] = o;
  }
}

// ---------------- fused bias+mask+pad table: [4 cls][8 h][64 n][64 m] f32 ----------------
__global__ __launch_bounds__(256) void btab_build(const float* __restrict__ rpb, float* __restrict__ btab) {
  const int cls = blockIdx.x >> 3, h = blockIdx.x & 7;
  float* dst = btab + (size_t)(cls * 8 + h) * 4096;
  for (int e = threadIdx.x; e < 4096; e += 256) {
    const int n = e >> 6, m = e & 63;
    float v;
    if (m >= 49) {
      v = -1e30f;
    } else if (n >= 49) {
      v = 0.f;
    } else {
      const int r1 = n / 7, c1 = n - r1 * 7;
      const int r2 = m / 7, c2 = m - r2 * 7;
      const int rel = (r1 - r2 + 6) * 13 + (c1 - c2 + 6);
      v = rpb[rel * 8 + h];
      const int reg1 = ((cls & 1) ? (r1 < 4 ? 1 : 2) : 0) * 3 + ((cls & 2) ? (c1 < 4 ? 1 : 2) : 0);
      const int reg2 = ((cls & 1) ? (r2 < 4 ? 1 : 2) : 0) * 3 + ((cls & 2) ? (c2 < 4 ? 1 : 2) : 0);
      if (reg1 != reg2) v -= 100.f;
    }
    dst[e] = v;
  }
}

// ---------------- LN1 + shift + window gather -> XY bf16 [CHUNK_ROWS][512] ----------------
__global__ __launch_bounds__(256) void ln_gather(
    const float* __restrict__ x, const float* __restrict__ y,
    const float* __restrict__ g1, const float* __restrict__ b1,
    u16* __restrict__ XY, int rowbase)
{
  const int wv = threadIdx.x >> 6, lane = threadIdx.x & 63;
  const int rl = blockIdx.x * 4 + wv;
  const int row = rowbase + rl;
  const int w = row / 49, n = row - w * 49;
  const int b = w >> 6, win = w & 63, wh = win >> 3, ww = win & 7;
  const int r = n / 7, c = n - r * 7;
  int oh = wh * 7 + r + 3; if (oh >= 56) oh -= 56;
  int ow = ww * 7 + c + 3; if (ow >= 56) ow -= 56;
  const size_t po = ((size_t)b * 3136 + oh * 56 + ow) * 256;
  const float4 g1v = ((const float4*)g1)[lane];
  const float4 b1v = ((const float4*)b1)[lane];
  u16* orow = XY + (size_t)rl * 512;
  #pragma unroll
  for (int mod = 0; mod < 2; ++mod) {
    const float* src = (mod ? y : x) + po;
    const float4 v = ((const float4*)src)[lane];
    float s = v.x + v.y + v.z + v.w;
    #pragma unroll
    for (int off = 1; off < 64; off <<= 1) s += __shfl_xor(s, off);
    const float mean = s * (1.0f / 256.0f);
    const float d0 = v.x - mean, d1 = v.y - mean, d2 = v.z - mean, d3 = v.w - mean;
    float sq = d0 * d0 + d1 * d1 + d2 * d2 + d3 * d3;
    #pragma unroll
    for (int off = 1; off < 64; off <<= 1) sq += __shfl_xor(sq, off);
    const float rstd = rsqrtf(sq * (1.0f / 256.0f) + 1e-5f);
    ushort4 o;
    o.x = f2bf(d0 * rstd * g1v.x + b1v.x);
    o.y = f2bf(d1 * rstd * g1v.y + b1v.y);
    o.z = f2bf(d2 * rstd * g1v.z + b1v.z);
    o.w = f2bf(d3 * rstd * g1v.w + b1v.w);
    *(ushort4*)(orow + mod * 256 + lane * 4) = o;
  }
}

// ---------------- QKV GEMM (128x128, XCD-swizzled): M=25088, N=1536, K=512 ----------------
__global__ __launch_bounds__(256) void qkv_gemm(
    const u16* __restrict__ A, const u16* __restrict__ Bw,
    const float* __restrict__ bias, u16* __restrict__ Qo)
{
  __shared__ __align__(16) u16 sA[128 * 64];
  __shared__ __align__(16) u16 sB[128 * 64];
  const int nx = gridDim.x;
  const int nwg = nx * gridDim.y;
  const int orig = blockIdx.y * nx + blockIdx.x;
  const int sw = (orig & 7) * (nwg >> 3) + (orig >> 3);
  const int m0  = (sw / nx) * 128;
  const int nn0 = (sw % nx) * 128;
  const int tid = threadIdx.x;
  const int lane = tid & 63;
  const int wv = tid >> 6;
  const int wm = wv >> 1, wn = wv & 1;
  const int rq = lane & 15, kg = lane >> 4;
  f32x4 acc[4][4];
  #pragma unroll
  for (int i = 0; i < 4; ++i)
    #pragma unroll
    for (int j = 0; j < 4; ++j) acc[i][j] = f32x4{0,0,0,0};

  for (int kt = 0; kt < 8; ++kt) {
    if (kt) __syncthreads();
    #pragma unroll
    for (int i = 0; i < 4; ++i) {
      const int c = i * 256 + tid;
      gload16(A + (size_t)(m0 + (c >> 3)) * 512 + kt * 64 + (c & 7) * 8, sA + c * 8);
    }
    #pragma unroll
    for (int i = 0; i < 4; ++i) {
      const int c = i * 256 + tid;
      gload16(Bw + (size_t)(nn0 + (c >> 3)) * 512 + kt * 64 + (c & 7) * 8, sB + c * 8);
    }
    __syncthreads();
    #pragma unroll
    for (int k0 = 0; k0 < 2; ++k0) {
      short8 af[4], bf8[4];
      #pragma unroll
      for (int mt = 0; mt < 4; ++mt)
        af[mt] = *(const short8*)(sA + (wm * 64 + mt * 16 + rq) * 64 + k0 * 32 + kg * 8);
      #pragma unroll
      for (int nt = 0; nt < 4; ++nt)
        bf8[nt] = *(const short8*)(sB + (wn * 64 + nt * 16 + rq) * 64 + k0 * 32 + kg * 8);
      #pragma unroll
      for (int mt = 0; mt < 4; ++mt)
        #pragma unroll
        for (int nt = 0; nt < 4; ++nt)
          acc[mt][nt] = mfma16(af[mt], bf8[nt], acc[mt][nt]);
    }
  }
  #pragma unroll
  for (int mt = 0; mt < 4; ++mt) {
    #pragma unroll
    for (int nt = 0; nt < 4; ++nt) {
      const int col = nn0 + wn * 64 + nt * 16 + rq;
      const int t = col >> 9, rem = col & 511;
      const int h = rem >> 6, d = rem & 63;
      const float bc = bias[col];
      const float sc = (t == 0) ? 0.17677669529663687f : 1.0f;
      u16* bp = Qo + (size_t)(t * 8 + h) * PLANE + d;
      #pragma unroll
      for (int r = 0; r < 4; ++r) {
        const int row = m0 + wm * 64 + mt * 16 + kg * 4 + r;
        bp[(size_t)row * 64] = f2bf((acc[mt][nt][r] + bc) * sc);
      }
    }
  }
}

// ---------------- barrier-free attention: one wave per (window, head), table-driven softmax ----------------
__global__ __launch_bounds__(256, 3) void attn3(
    const u16* __restrict__ qkv, const float* __restrict__ btab,
    u16* __restrict__ concat, int wbase)
{
  __shared__ __align__(16) u16 sP[4][3136];    // per-wave P / out buffer (49 x 64, swizzled)
  __shared__ __align__(16) u16 sVT[4][4608];   // per-wave vT: [d][tok^((d>>3)&3)<<4], stride 72

  const int tid = threadIdx.x;
  const int wv = tid >> 6, lane = tid & 63;
  const int rq = lane & 15, kg = lane >> 4;
  const int gw = blockIdx.x * 4 + wv;
  const int wl = gw >> 3, h = gw & 7;
  const int w = wbase + wl;
  const int win = w & 63, wh = win >> 3, ww = win & 7;
  const int cls = ((wh == 7) ? 1 : 0) | ((ww == 7) ? 2 : 0);
  const float* Tb = btab + (size_t)(cls * 8 + h) * 4096;
  u16* sPw = sP[wv];
  u16* sVw = sVT[wv];

  const u16* qbase = qkv + (size_t)h * PLANE + (size_t)wl * 49 * 64;
  const u16* kbase = qkv + KOFF + (size_t)h * PLANE + (size_t)wl * 49 * 64;
  const u16* vbase = qkv + VOFF + (size_t)h * PLANE + (size_t)wl * 49 * 64;

  // ---- issue v row loads early (hidden under QK^T) ----
  short8 vreg[4][2];
  #pragma unroll
  for (int t = 0; t < 4; ++t)
    #pragma unroll
    for (int h2 = 0; h2 < 2; ++h2)
      vreg[t][h2] = *(const short8*)(vbase + (size_t)(16 * t + rq) * 64 + kg * 8 + h2 * 32);

  // ---- K fragments (all), then S with per-i Q loads ----
  short8 ak[4][2];
  #pragma unroll
  for (int j = 0; j < 4; ++j) {
    const int rr = (16 * j + rq) > 48 ? 48 : (16 * j + rq);
    ak[j][0] = *(const short8*)(kbase + rr * 64 + kg * 8);
    ak[j][1] = *(const short8*)(kbase + rr * 64 + 32 + kg * 8);
  }
  f32x4 sacc[4][4];
  #pragma unroll
  for (int i = 0; i < 4; ++i)
    #pragma unroll
    for (int j = 0; j < 4; ++j) sacc[i][j] = f32x4{0,0,0,0};
  #pragma unroll
  for (int i = 0; i < 4; ++i) {
    const int rr = (16 * i + rq) > 48 ? 48 : (16 * i + rq);
    const short8 a0 = *(const short8*)(qbase + rr * 64 + kg * 8);
    const short8 a1 = *(const short8*)(qbase + rr * 64 + 32 + kg * 8);
    #pragma unroll
    for (int j = 0; j < 4; ++j) {
      sacc[i][j] = mfma16(a0, ak[j][0], sacc[i][j]);
      sacc[i][j] = mfma16(a1, ak[j][1], sacc[i][j]);
    }
  }

  // ---- write v into LDS vT (conflict-free: row ^ (kg<<4)) ----
  #pragma unroll
  for (int t = 0; t < 4; ++t) {
    const int row = 16 * t + rq;
    #pragma unroll
    for (int h2 = 0; h2 < 2; ++h2) {
      const int c0 = kg * 8 + h2 * 32;
      #pragma unroll
      for (int j = 0; j < 8; ++j)
        sVw[(c0 + j) * 72 + (row ^ (kg << 4))] = (u16)vreg[t][h2][j];
    }
  }

  // ---- table-driven softmax; P -> sPw (swizzled) ----
  #pragma unroll
  for (int i = 0; i < 4; ++i) {
    #pragma unroll
    for (int r = 0; r < 4; ++r) {
      const int n = 16 * i + kg * 4 + r;
      const float* Trow = Tb + n * 64 + rq;
      float pv[4];
      #pragma unroll
      for (int j = 0; j < 4; ++j)
        pv[j] = sacc[i][j][r] + Trow[16 * j];
      float mx = fmaxf(fmaxf(pv[0], pv[1]), fmaxf(pv[2], pv[3]));
      #pragma unroll
      for (int off = 1; off < 16; off <<= 1) mx = fmaxf(mx, __shfl_xor(mx, off));
      float sm = 0.f;
      #pragma unroll
      for (int j = 0; j < 4; ++j) { const float e = __expf(pv[j] - mx); pv[j] = e; sm += e; }
      #pragma unroll
      for (int off = 1; off < 16; off <<= 1) sm += __shfl_xor(sm, off);
      const float inv = 1.0f / sm;
      if (n < 49) {
        #pragma unroll
        for (int j = 0; j < 4; ++j) {
          const int col = 16 * j + rq;
          sPw[n * 64 + (((col >> 3) ^ (n & 7)) << 3) + (col & 7)] = f2bf(pv[j] * inv);
        }
      }
    }
  }

  // ---- PV: A = P (LDS), B = vT (LDS b128, pad toks masked) ----
  f32x4 oacc[4][4];
  #pragma unroll
  for (int i = 0; i < 4; ++i)
    #pragma unroll
    for (int j = 0; j < 4; ++j) oacc[i][j] = f32x4{0,0,0,0};
  #pragma unroll
  for (int m0v = 0; m0v < 2; ++m0v) {
    short8 av[4];
    #pragma unroll
    for (int ct = 0; ct < 4; ++ct) {
      const int col = ct * 16 + rq;
      const int s = (col >> 3) & 3;
      short8 vvv = *(const short8*)(sVw + col * 72 + ((m0v * 32 + kg * 8) ^ (s << 4)));
      if (m0v == 1) {
        if (kg == 3) {
          #pragma unroll
          for (int e = 0; e < 8; ++e) vvv[e] = 0;
        } else if (kg == 2) {
          #pragma unroll
          for (int e = 1; e < 8; ++e) vvv[e] = 0;
        }
      }
      av[ct] = vvv;
    }
    #pragma unroll
    for (int i = 0; i < 4; ++i) {
      const int rr = (16 * i + rq) > 48 ? 48 : (16 * i + rq);
      const int ch = (m0v * 4 + kg) ^ (rr & 7);
      const short8 pa = *(const short8*)(sPw + rr * 64 + ch * 8);
      #pragma unroll
      for (int ct = 0; ct < 4; ++ct)
        oacc[i][ct] = mfma16(pa, av[ct], oacc[i][ct]);
    }
  }

  // ---- repack out_h through LDS (reuse sPw), coalesced b128 store ----
  __builtin_amdgcn_s_waitcnt(0);
  #pragma unroll
  for (int i = 0; i < 4; ++i)
    #pragma unroll
    for (int ct = 0; ct < 4; ++ct)
      #pragma unroll
      for (int r = 0; r < 4; ++r) {
        const int n = 16 * i + kg * 4 + r;
        if (n < 49) {
          const int col = ct * 16 + rq;
          sPw[n * 64 + (((col >> 3) ^ (n & 7)) << 3) + (col & 7)] = f2bf(oacc[i][ct][r]);
        }
      }
  u16* crow = concat + (size_t)(wl * 49) * 512 + h * 64;
  #pragma unroll
  for (int it = 0; it < 7; ++it) {
    const int c = it * 64 + lane;
    if (c < 392) {
      const int m = c >> 3, s = c & 7;
      const short8 vvv = *(const short8*)(sPw + m * 64 + ((s ^ (m & 7)) << 3));
      *(short8*)(crow + (size_t)m * 512 + s * 8) = vvv;
    }
  }
}

// ---------------- proj GEMM + LN2 fused: BM=128, BN=256 (full row); grid 196 ----------------
__global__ __launch_bounds__(256, 2) void projln(
    const u16* __restrict__ A, const u16* __restrict__ Bw,
    const float* __restrict__ bias, const float* __restrict__ x,
    const float* __restrict__ g2, const float* __restrict__ b2,
    float* __restrict__ out, u16* __restrict__ xn2, int rowbase)
{
  __shared__ __align__(16) u16 sA[128 * 64];
  __shared__ __align__(16) u16 sB[256 * 64];
  const int m0 = blockIdx.x * 128;
  const int tid = threadIdx.x;
  const int lane = tid & 63;
  const int wv = tid >> 6;
  const int rq = lane & 15, kg = lane >> 4;
  f32x4 acc[2][16];
  #pragma unroll
  for (int i = 0; i < 2; ++i)
    #pragma unroll
    for (int j = 0; j < 16; ++j) acc[i][j] = f32x4{0,0,0,0};

  for (int kt = 0; kt < 8; ++kt) {
    if (kt) __syncthreads();
    #pragma unroll
    for (int i = 0; i < 4; ++i) {
      const int c = i * 256 + tid;
      gload16(A + (size_t)(m0 + (c >> 3)) * 512 + kt * 64 + (c & 7) * 8, sA + c * 8);
    }
    #pragma unroll
    for (int i = 0; i < 8; ++i) {
      const int c = i * 256 + tid;
      gload16(Bw + (size_t)(c >> 3) * 512 + kt * 64 + (c & 7) * 8, sB + c * 8);
    }
    __syncthreads();
    #pragma unroll
    for (int k0 = 0; k0 < 2; ++k0) {
      short8 af[2];
      #pragma unroll
      for (int mt = 0; mt < 2; ++mt)
        af[mt] = *(const short8*)(sA + (wv * 32 + mt * 16 + rq) * 64 + k0 * 32 + kg * 8);
      #pragma unroll
      for (int nt = 0; nt < 16; ++nt) {
        const short8 bf8 = *(const short8*)(sB + (nt * 16 + rq) * 64 + k0 * 32 + kg * 8);
        #pragma unroll
        for (int mt = 0; mt < 2; ++mt)
          acc[mt][nt] = mfma16(af[mt], bf8, acc[mt][nt]);
      }
    }
  }

  float br[16], g2r[16], b2r[16];
  #pragma unroll
  for (int nt = 0; nt < 16; ++nt) {
    const int col = nt * 16 + rq;
    br[nt] = bias[col]; g2r[nt] = g2[col]; b2r[nt] = b2[col];
  }
  #pragma unroll
  for (int mt = 0; mt < 2; ++mt) {
    #pragma unroll
    for (int r = 0; r < 4; ++r) {
      const int row = m0 + wv * 32 + mt * 16 + kg * 4 + r;
      const u32 g = (u32)(rowbase + row);
      const u32 w = g / 49u; const u32 n = g - w * 49u;
      const int b = w >> 6, win = w & 63, wh = win >> 3, ww = win & 7;
      const u32 rr = n / 7u; const u32 cc = n - rr * 7u;
      int oh = wh * 7 + (int)rr + 3; if (oh >= 56) oh -= 56;
      int ow = ww * 7 + (int)cc + 3; if (ow >= 56) ow -= 56;
      const size_t po = ((size_t)b * 3136 + oh * 56 + ow) * 256;
      float vals[16];
      float s = 0.f;
      #pragma unroll
      for (int nt = 0; nt < 16; ++nt) {
        const float v = acc[mt][nt][r] + br[nt] + x[po + nt * 16 + rq];
        vals[nt] = v; s += v;
      }
      #pragma unroll
      for (int off = 1; off < 16; off <<= 1) s += __shfl_xor(s, off);
      const float mean = s * (1.0f / 256.0f);
      float sq = 0.f;
      #pragma unroll
      for (int nt = 0; nt < 16; ++nt) { const float d_ = vals[nt] - mean; sq += d_ * d_; }
      #pragma unroll
      for (int off = 1; off < 16; off <<= 1) sq += __shfl_xor(sq, off);
      const float rstd = rsqrtf(sq * (1.0f / 256.0f) + 1e-5f);
      #pragma unroll
      for (int nt = 0; nt < 16; ++nt) {
        const int col = nt * 16 + rq;
        out[po + col] = vals[nt];
        xn2[po + col] = f2bf((vals[nt] - mean) * rstd * g2r[nt] + b2r[nt]);
      }
    }
  }
}

// ---------------- fused MLP: fc1 + GELU + fc2 + residual, h stays in LDS ----------------
// one block per 64 rows; grid 1568. B-frags direct from L2-resident weights,
// per-wave-distinct cols/rows (no redundant loads). XOR-swizzled LDS tiles.
__global__ __launch_bounds__(256, 3) void fused_mlp(
    const u16* __restrict__ xn2, const u16* __restrict__ w1,
    const float* __restrict__ bf1, const u16* __restrict__ w2,
    const float* __restrict__ bf2v, float* __restrict__ out)
{
  __shared__ __align__(16) u16 sX[64 * 256];   // xn2 panel, chunk-swizzled
  __shared__ __align__(16) u16 sH[64 * 128];   // h tile, chunk-swizzled

  const int m0 = blockIdx.x * 64;
  const int tid = threadIdx.x;
  const int wv = tid >> 6, lane = tid & 63;
  const int rq = lane & 15, kg = lane >> 4;

  // stage xn2 panel (pre-swizzled global source, linear LDS dest)
  #pragma unroll
  for (int i = 0; i < 8; ++i) {
    const int c = i * 256 + tid;
    const int row = c >> 5, ch = c & 31;
    const int sch = (ch & 24) | ((ch ^ row) & 7);
    gload16(xn2 + (size_t)(m0 + row) * 256 + sch * 8, sX + c * 8);
  }

  f32x4 acc2[4][4];
  #pragma unroll
  for (int i = 0; i < 4; ++i)
    #pragma unroll
    for (int j = 0; j < 4; ++j) acc2[i][j] = f32x4{0,0,0,0};

  __syncthreads();

  for (int t = 0; t < 8; ++t) {
    // ---- fc1: this wave's 32 h-cols of tile t (cols t*128 + wv*32 + ...) ----
    f32x4 a1[4][2];
    #pragma unroll
    for (int i = 0; i < 4; ++i)
      #pragma unroll
      for (int j = 0; j < 2; ++j) a1[i][j] = f32x4{0,0,0,0};
    #pragma unroll
    for (int ks = 0; ks < 8; ++ks) {
      short8 bfr[2];
      #pragma unroll
      for (int nt = 0; nt < 2; ++nt)
        bfr[nt] = *(const short8*)(w1 + (size_t)(t * 128 + wv * 32 + nt * 16 + rq) * 256 + ks * 32 + kg * 8);
      #pragma unroll
      for (int mt = 0; mt < 4; ++mt) {
        const int R = mt * 16 + rq;
        const int wk = ks * 4 + kg;
        const short8 af = *(const short8*)(sX + R * 256 + ((wk & 24) | ((wk ^ R) & 7)) * 8);
        #pragma unroll
        for (int nt = 0; nt < 2; ++nt)
          a1[mt][nt] = mfma16(af, bfr[nt], a1[mt][nt]);
      }
    }
    __syncthreads();   // previous tile's fc2 reads of sH complete
    // ---- bias + GELU, write h tile (swizzled) ----
    #pragma unroll
    for (int nt = 0; nt < 2; ++nt) {
      const int col = wv * 32 + nt * 16 + rq;
      const float bb = bf1[t * 128 + col];
      const int ch = col >> 3;
      #pragma unroll
      for (int mt = 0; mt < 4; ++mt)
        #pragma unroll
        for (int r = 0; r < 4; ++r) {
          const int row = mt * 16 + kg * 4 + r;
          sH[row * 128 + ((ch & 8) | ((ch ^ row) & 7)) * 8 + (col & 7)] =
              f2bf(gelu_t(a1[mt][nt][r] + bb));
        }
    }
    __syncthreads();   // h tile visible
    // ---- fc2 partial: all 64 rows x this wave's 64 cols, k = t*128..+128 ----
    #pragma unroll
    for (int ks = 0; ks < 4; ++ks) {
      short8 bfr2[4];
      #pragma unroll
      for (int nt = 0; nt < 4; ++nt)
        bfr2[nt] = *(const short8*)(w2 + (size_t)(wv * 64 + nt * 16 + rq) * 1024 + t * 128 + ks * 32 + kg * 8);
      #pragma unroll
      for (int mt = 0; mt < 4; ++mt) {
        const int R = mt * 16 + rq;
        const int wk = ks * 4 + kg;
        const short8 af = *(const short8*)(sH + R * 128 + ((wk & 8) | ((wk ^ R) & 7)) * 8);
        #pragma unroll
        for (int nt = 0; nt < 4; ++nt)
          acc2[mt][nt] = mfma16(af, bfr2[nt], acc2[mt][nt]);
      }
    }
  }

  // ---- epilogue: + b_fc2 + residual RMW ----
  #pragma unroll
  for (int nt = 0; nt < 4; ++nt) {
    const int col = wv * 64 + nt * 16 + rq;
    const float bb = bf2v[col];
    #pragma unroll
    for (int mt = 0; mt < 4; ++mt)
      #pragma unroll
      for (int r = 0; r < 4; ++r) {
        float* p = out + (size_t)(m0 + mt * 16 + kg * 4 + r) * 256 + col;
        *p = acc2[mt][nt][r] + bb + *p;
      }
  }
}

extern "C" void kernel_launch(void* const* d_in, const int* in_sizes, int n_in,
                              void* d_out, int out_size, void* d_ws, size_t ws_size,
                              hipStream_t stream) {
  const float* x      = (const float*)d_in[0];
  const float* y      = (const float*)d_in[1];
  const float* g1     = (const float*)d_in[2];
  const float* b1     = (const float*)d_in[3];
  const float* rpb    = (const float*)d_in[4];
  const float* w_qkv  = (const float*)d_in[5];
  const float* b_qkv  = (const float*)d_in[6];
  const float* w_proj = (const float*)d_in[7];
  const float* b_proj = (const float*)d_in[8];
  const float* g2     = (const float*)d_in[9];
  const float* b2     = (const float*)d_in[10];
  const float* w_fc1  = (const float*)d_in[11];
  const float* b_fc1  = (const float*)d_in[12];
  const float* w_fc2  = (const float*)d_in[13];
  const float* b_fc2  = (const float*)d_in[14];
  float* out = (float*)d_out;

  u16* wsp = (u16*)d_ws;
  u16* wqkv_bf  = wsp;                       //  786432
  u16* wproj_bf = wsp + 786432;              //  131072
  u16* wfc1_bf  = wsp + 917504;              //  262144
  u16* wfc2_bf  = wsp + 1179648;             //  262144
  float* btab   = (float*)(wsp + 1441792);   //  131072 f32
  u16* xn2      = wsp + 1703936;             //  25690112
  u16* XYc      = wsp + 27394048;            //  12845056 (25088 x 512)
  u16* qkvc     = wsp + 40239104;            //  24 planes x 25088 x 64

  convk<<<768, 256, 0, stream>>>(w_qkv,  wqkv_bf,  196608);
  convk<<<128, 256, 0, stream>>>(w_proj, wproj_bf, 32768);
  convk<<<256, 256, 0, stream>>>(w_fc1,  wfc1_bf,  65536);
  convk<<<256, 256, 0, stream>>>(w_fc2,  wfc2_bf,  65536);
  btab_build<<<32, 256, 0, stream>>>(rpb, btab);

  for (int c = 0; c < 4; ++c) {
    ln_gather<<<6272, 256, 0, stream>>>(x, y, g1, b1, XYc, c * CHUNK_ROWS);
    qkv_gemm<<<dim3(12, 196), 256, 0, stream>>>(XYc, wqkv_bf, b_qkv, qkvc);
    attn3<<<1024, 256, 0, stream>>>(qkvc, btab, XYc, c * 512);
    projln<<<196, 256, 0, stream>>>(XYc, wproj_bf, b_proj, x, g2, b2, out, xn2, c * CHUNK_ROWS);
  }

  fused_mlp<<<1568, 256, 0, stream>>>(xn2, wfc1_bf, b_fc1, wfc2_bf, b_fc2, out);
}

// Round 9
// 854.120 us; speedup vs baseline: 1.4074x; 1.0142x over previous
//
#include <hip/hip_runtime.h>
#include <hip/hip_bf16.h>

#define DEVI __device__ __forceinline__

typedef __attribute__((ext_vector_type(8))) short short8;
typedef __attribute__((ext_vector_type(4))) float f32x4;
typedef unsigned int u32;
typedef unsigned short u16;

typedef __attribute__((address_space(1))) const u32 gu32_t;
typedef __attribute__((address_space(3))) u32 lu32_t;

DEVI u16 f2bf(float f) {
  u32 u = __builtin_bit_cast(u32, f);
  u32 r = (u + 0x7fffu + ((u >> 16) & 1u)) >> 16;
  return (u16)r;
}

DEVI f32x4 mfma16(short8 a, short8 b, f32x4 c) {
  return __builtin_amdgcn_mfma_f32_16x16x32_bf16(a, b, c, 0, 0, 0);
}

DEVI void gload16(const void* g, void* l) {
  __builtin_amdgcn_global_load_lds((gu32_t*)g, (lu32_t*)l, 16, 0, 0);
}

DEVI float gelu_t(float v) {
  const float u = v * (0.7978845608f + 0.0356774081f * v * v);
  const float t = 1.0f - 2.0f / (__expf(2.0f * u) + 1.0f);
  return 0.5f * v * (1.0f + t);
}

#define CHUNK_ROWS 25088   // 512 windows * 49 tokens
#define PLANE ((size_t)CHUNK_ROWS * 64)
#define KOFF  ((size_t)8 * PLANE)          // k planes base
#define VOFF  ((size_t)16 * PLANE)         // v planes base (linear)

// ---------------- weight f32 -> bf16 ----------------
__global__ __launch_bounds__(256) void convk(const float* __restrict__ s, u16* __restrict__ d, int n4) {
  int i = blockIdx.x * 256 + threadIdx.x;
  if (i < n4) {
    const float4 v = ((const float4*)s)[i];
    ushort4 o;
    o.x = f2bf(v.x); o.y = f2bf(v.y); o.z = f2bf(v.z); o.w = f2bf(v.w);
    ((ushort4*)d)[i] = o;
  }
}

// ---------------- fused bias+mask+pad table: [4 cls][8 h][64 n][64 m] f32 ----------------
__global__ __launch_bounds__(256) void btab_build(const float* __restrict__ rpb, float* __restrict__ btab) {
  const int cls = blockIdx.x >> 3, h = blockIdx.x & 7;
  float* dst = btab + (size_t)(cls * 8 + h) * 4096;
  for (int e = threadIdx.x; e < 4096; e += 256) {
    const int n = e >> 6, m = e & 63;
    float v;
    if (m >= 49) {
      v = -1e30f;
    } else if (n >= 49) {
      v = 0.f;
    } else {
      const int r1 = n / 7, c1 = n - r1 * 7;
      const int r2 = m / 7, c2 = m - r2 * 7;
      const int rel = (r1 - r2 + 6) * 13 + (c1 - c2 + 6);
      v = rpb[rel * 8 + h];
      const int reg1 = ((cls & 1) ? (r1 < 4 ? 1 : 2) : 0) * 3 + ((cls & 2) ? (c1 < 4 ? 1 : 2) : 0);
      const int reg2 = ((cls & 1) ? (r2 < 4 ? 1 : 2) : 0) * 3 + ((cls & 2) ? (c2 < 4 ? 1 : 2) : 0);
      if (reg1 != reg2) v -= 100.f;
    }
    dst[e] = v;
  }
}

// ---------------- LN1 + shift + window gather -> XY bf16 [CHUNK_ROWS][512] ----------------
__global__ __launch_bounds__(256) void ln_gather(
    const float* __restrict__ x, const float* __restrict__ y,
    const float* __restrict__ g1, const float* __restrict__ b1,
    u16* __restrict__ XY, int rowbase)
{
  const int wv = threadIdx.x >> 6, lane = threadIdx.x & 63;
  const int rl = blockIdx.x * 4 + wv;
  const int row = rowbase + rl;
  const int w = row / 49, n = row - w * 49;
  const int b = w >> 6, win = w & 63, wh = win >> 3, ww = win & 7;
  const int r = n / 7, c = n - r * 7;
  int oh = wh * 7 + r + 3; if (oh >= 56) oh -= 56;
  int ow = ww * 7 + c + 3; if (ow >= 56) ow -= 56;
  const size_t po = ((size_t)b * 3136 + oh * 56 + ow) * 256;
  const float4 g1v = ((const float4*)g1)[lane];
  const float4 b1v = ((const float4*)b1)[lane];
  u16* orow = XY + (size_t)rl * 512;
  #pragma unroll
  for (int mod = 0; mod < 2; ++mod) {
    const float* src = (mod ? y : x) + po;
    const float4 v = ((const float4*)src)[lane];
    float s = v.x + v.y + v.z + v.w;
    #pragma unroll
    for (int off = 1; off < 64; off <<= 1) s += __shfl_xor(s, off);
    const float mean = s * (1.0f / 256.0f);
    const float d0 = v.x - mean, d1 = v.y - mean, d2 = v.z - mean, d3 = v.w - mean;
    float sq = d0 * d0 + d1 * d1 + d2 * d2 + d3 * d3;
    #pragma unroll
    for (int off = 1; off < 64; off <<= 1) sq += __shfl_xor(sq, off);
    const float rstd = rsqrtf(sq * (1.0f / 256.0f) + 1e-5f);
    ushort4 o;
    o.x = f2bf(d0 * rstd * g1v.x + b1v.x);
    o.y = f2bf(d1 * rstd * g1v.y + b1v.y);
    o.z = f2bf(d2 * rstd * g1v.z + b1v.z);
    o.w = f2bf(d3 * rstd * g1v.w + b1v.w);
    *(ushort4*)(orow + mod * 256 + lane * 4) = o;
  }
}

// ---------------- QKV GEMM (128x128, XCD-swizzled): M=25088, N=1536, K=512 ----------------
// C-tile routed through LDS (overlay of sA/sB) -> coalesced b128 stores per head.
__global__ __launch_bounds__(256) void qkv_gemm(
    const u16* __restrict__ A, const u16* __restrict__ Bw,
    const float* __restrict__ bias, u16* __restrict__ Qo)
{
  __shared__ __align__(16) u16 smem[128 * 128];   // 32 KB: sA|sB during K loop, C-tile after
  u16* sA = smem;
  u16* sB = smem + 128 * 64;
  const int nx = gridDim.x;
  const int nwg = nx * gridDim.y;
  const int orig = blockIdx.y * nx + blockIdx.x;
  const int sw = (orig & 7) * (nwg >> 3) + (orig >> 3);
  const int m0  = (sw / nx) * 128;
  const int nn0 = (sw % nx) * 128;
  const int tid = threadIdx.x;
  const int lane = tid & 63;
  const int wv = tid >> 6;
  const int wm = wv >> 1, wn = wv & 1;
  const int rq = lane & 15, kg = lane >> 4;
  f32x4 acc[4][4];
  #pragma unroll
  for (int i = 0; i < 4; ++i)
    #pragma unroll
    for (int j = 0; j < 4; ++j) acc[i][j] = f32x4{0,0,0,0};

  for (int kt = 0; kt < 8; ++kt) {
    if (kt) __syncthreads();
    #pragma unroll
    for (int i = 0; i < 4; ++i) {
      const int c = i * 256 + tid;
      gload16(A + (size_t)(m0 + (c >> 3)) * 512 + kt * 64 + (c & 7) * 8, sA + c * 8);
    }
    #pragma unroll
    for (int i = 0; i < 4; ++i) {
      const int c = i * 256 + tid;
      gload16(Bw + (size_t)(nn0 + (c >> 3)) * 512 + kt * 64 + (c & 7) * 8, sB + c * 8);
    }
    __syncthreads();
    #pragma unroll
    for (int k0 = 0; k0 < 2; ++k0) {
      short8 af[4], bf8[4];
      #pragma unroll
      for (int mt = 0; mt < 4; ++mt)
        af[mt] = *(const short8*)(sA + (wm * 64 + mt * 16 + rq) * 64 + k0 * 32 + kg * 8);
      #pragma unroll
      for (int nt = 0; nt < 4; ++nt)
        bf8[nt] = *(const short8*)(sB + (wn * 64 + nt * 16 + rq) * 64 + k0 * 32 + kg * 8);
      #pragma unroll
      for (int mt = 0; mt < 4; ++mt)
        #pragma unroll
        for (int nt = 0; nt < 4; ++nt)
          acc[mt][nt] = mfma16(af[mt], bf8[nt], acc[mt][nt]);
    }
  }
  // ---- C tile -> LDS (swizzled), then coalesced stores ----
  __syncthreads();
  const int t = nn0 >> 9;
  const int hbase = (nn0 & 511) >> 6;
  const float sc = (t == 0) ? 0.17677669529663687f : 1.0f;
  #pragma unroll
  for (int nt = 0; nt < 4; ++nt) {
    const int col = wn * 64 + nt * 16 + rq;           // local 0..127
    const float bc = bias[nn0 + col];
    const int c = col >> 3;
    #pragma unroll
    for (int mt = 0; mt < 4; ++mt)
      #pragma unroll
      for (int r = 0; r < 4; ++r) {
        const int row = wm * 64 + mt * 16 + kg * 4 + r;  // local 0..127
        smem[row * 128 + (((c & 8) | ((c ^ row) & 7)) << 3) + (col & 7)] =
            f2bf((acc[mt][nt][r] + bc) * sc);
      }
  }
  __syncthreads();
  #pragma unroll
  for (int it = 0; it < 8; ++it) {
    const int cc = it * 256 + tid;
    const int row = cc >> 4, c = cc & 15;
    const int col = c * 8;
    const int hh = col >> 6, d = col & 63;
    const short8 v = *(const short8*)(smem + row * 128 + (((c & 8) | ((c ^ row) & 7)) << 3));
    *(short8*)(Qo + (size_t)(t * 8 + hbase + hh) * PLANE + (size_t)(m0 + row) * 64 + d) = v;
  }
}

// ---------------- barrier-free attention: one wave per (window, head), table-driven softmax ----------------
__global__ __launch_bounds__(256, 3) void attn3(
    const u16* __restrict__ qkv, const float* __restrict__ btab,
    u16* __restrict__ concat, int wbase)
{
  __shared__ __align__(16) u16 sP[4][3136];    // per-wave P / out buffer (49 x 64, swizzled)
  __shared__ __align__(16) u16 sVT[4][4608];   // per-wave vT: [d][tok^((d>>3)&3)<<4], stride 72

  const int tid = threadIdx.x;
  const int wv = tid >> 6, lane = tid & 63;
  const int rq = lane & 15, kg = lane >> 4;
  const int gw = blockIdx.x * 4 + wv;
  const int wl = gw >> 3, h = gw & 7;
  const int w = wbase + wl;
  const int win = w & 63, wh = win >> 3, ww = win & 7;
  const int cls = ((wh == 7) ? 1 : 0) | ((ww == 7) ? 2 : 0);
  const float* Tb = btab + (size_t)(cls * 8 + h) * 4096;
  u16* sPw = sP[wv];
  u16* sVw = sVT[wv];

  const u16* qbase = qkv + (size_t)h * PLANE + (size_t)wl * 49 * 64;
  const u16* kbase = qkv + KOFF + (size_t)h * PLANE + (size_t)wl * 49 * 64;
  const u16* vbase = qkv + VOFF + (size_t)h * PLANE + (size_t)wl * 49 * 64;

  // ---- issue v row loads early (hidden under QK^T) ----
  short8 vreg[4][2];
  #pragma unroll
  for (int t = 0; t < 4; ++t)
    #pragma unroll
    for (int h2 = 0; h2 < 2; ++h2)
      vreg[t][h2] = *(const short8*)(vbase + (size_t)(16 * t + rq) * 64 + kg * 8 + h2 * 32);

  // ---- K fragments (all), then S with per-i Q loads ----
  short8 ak[4][2];
  #pragma unroll
  for (int j = 0; j < 4; ++j) {
    const int rr = (16 * j + rq) > 48 ? 48 : (16 * j + rq);
    ak[j][0] = *(const short8*)(kbase + rr * 64 + kg * 8);
    ak[j][1] = *(const short8*)(kbase + rr * 64 + 32 + kg * 8);
  }
  f32x4 sacc[4][4];
  #pragma unroll
  for (int i = 0; i < 4; ++i)
    #pragma unroll
    for (int j = 0; j < 4; ++j) sacc[i][j] = f32x4{0,0,0,0};
  #pragma unroll
  for (int i = 0; i < 4; ++i) {
    const int rr = (16 * i + rq) > 48 ? 48 : (16 * i + rq);
    const short8 a0 = *(const short8*)(qbase + rr * 64 + kg * 8);
    const short8 a1 = *(const short8*)(qbase + rr * 64 + 32 + kg * 8);
    #pragma unroll
    for (int j = 0; j < 4; ++j) {
      sacc[i][j] = mfma16(a0, ak[j][0], sacc[i][j]);
      sacc[i][j] = mfma16(a1, ak[j][1], sacc[i][j]);
    }
  }

  // ---- write v into LDS vT (conflict-free: row ^ (kg<<4)) ----
  #pragma unroll
  for (int t = 0; t < 4; ++t) {
    const int row = 16 * t + rq;
    #pragma unroll
    for (int h2 = 0; h2 < 2; ++h2) {
      const int c0 = kg * 8 + h2 * 32;
      #pragma unroll
      for (int j = 0; j < 8; ++j)
        sVw[(c0 + j) * 72 + (row ^ (kg << 4))] = (u16)vreg[t][h2][j];
    }
  }

  // ---- table-driven softmax; P -> sPw (swizzled) ----
  #pragma unroll
  for (int i = 0; i < 4; ++i) {
    #pragma unroll
    for (int r = 0; r < 4; ++r) {
      const int n = 16 * i + kg * 4 + r;
      const float* Trow = Tb + n * 64 + rq;
      float pv[4];
      #pragma unroll
      for (int j = 0; j < 4; ++j)
        pv[j] = sacc[i][j][r] + Trow[16 * j];
      float mx = fmaxf(fmaxf(pv[0], pv[1]), fmaxf(pv[2], pv[3]));
      #pragma unroll
      for (int off = 1; off < 16; off <<= 1) mx = fmaxf(mx, __shfl_xor(mx, off));
      float sm = 0.f;
      #pragma unroll
      for (int j = 0; j < 4; ++j) { const float e = __expf(pv[j] - mx); pv[j] = e; sm += e; }
      #pragma unroll
      for (int off = 1; off < 16; off <<= 1) sm += __shfl_xor(sm, off);
      const float inv = 1.0f / sm;
      if (n < 49) {
        #pragma unroll
        for (int j = 0; j < 4; ++j) {
          const int col = 16 * j + rq;
          sPw[n * 64 + (((col >> 3) ^ (n & 7)) << 3) + (col & 7)] = f2bf(pv[j] * inv);
        }
      }
    }
  }

  // ---- PV: A = P (LDS), B = vT (LDS b128, pad toks masked) ----
  f32x4 oacc[4][4];
  #pragma unroll
  for (int i = 0; i < 4; ++i)
    #pragma unroll
    for (int j = 0; j < 4; ++j) oacc[i][j] = f32x4{0,0,0,0};
  #pragma unroll
  for (int m0v = 0; m0v < 2; ++m0v) {
    short8 av[4];
    #pragma unroll
    for (int ct = 0; ct < 4; ++ct) {
      const int col = ct * 16 + rq;
      const int s = (col >> 3) & 3;
      short8 vvv = *(const short8*)(sVw + col * 72 + ((m0v * 32 + kg * 8) ^ (s << 4)));
      if (m0v == 1) {
        if (kg == 3) {
          #pragma unroll
          for (int e = 0; e < 8; ++e) vvv[e] = 0;
        } else if (kg == 2) {
          #pragma unroll
          for (int e = 1; e < 8; ++e) vvv[e] = 0;
        }
      }
      av[ct] = vvv;
    }
    #pragma unroll
    for (int i = 0; i < 4; ++i) {
      const int rr = (16 * i + rq) > 48 ? 48 : (16 * i + rq);
      const int ch = (m0v * 4 + kg) ^ (rr & 7);
      const short8 pa = *(const short8*)(sPw + rr * 64 + ch * 8);
      #pragma unroll
      for (int ct = 0; ct < 4; ++ct)
        oacc[i][ct] = mfma16(pa, av[ct], oacc[i][ct]);
    }
  }

  // ---- repack out_h through LDS (reuse sPw), coalesced b128 store ----
  __builtin_amdgcn_s_waitcnt(0);
  #pragma unroll
  for (int i = 0; i < 4; ++i)
    #pragma unroll
    for (int ct = 0; ct < 4; ++ct)
      #pragma unroll
      for (int r = 0; r < 4; ++r) {
        const int n = 16 * i + kg * 4 + r;
        if (n < 49) {
          const int col = ct * 16 + rq;
          sPw[n * 64 + (((col >> 3) ^ (n & 7)) << 3) + (col & 7)] = f2bf(oacc[i][ct][r]);
        }
      }
  u16* crow = concat + (size_t)(wl * 49) * 512 + h * 64;
  #pragma unroll
  for (int it = 0; it < 7; ++it) {
    const int c = it * 64 + lane;
    if (c < 392) {
      const int m = c >> 3, s = c & 7;
      const short8 vvv = *(const short8*)(sPw + m * 64 + ((s ^ (m & 7)) << 3));
      *(short8*)(crow + (size_t)m * 512 + s * 8) = vvv;
    }
  }
}

// ---------------- proj GEMM + LN2 fused: BM=128, BN=256 (full row); grid 196 ----------------
__global__ __launch_bounds__(256, 2) void projln(
    const u16* __restrict__ A, const u16* __restrict__ Bw,
    const float* __restrict__ bias, const float* __restrict__ x,
    const float* __restrict__ g2, const float* __restrict__ b2,
    float* __restrict__ out, u16* __restrict__ xn2, int rowbase)
{
  __shared__ __align__(16) u16 sA[128 * 64];
  __shared__ __align__(16) u16 sB[256 * 64];
  const int m0 = blockIdx.x * 128;
  const int tid = threadIdx.x;
  const int lane = tid & 63;
  const int wv = tid >> 6;
  const int rq = lane & 15, kg = lane >> 4;
  f32x4 acc[2][16];
  #pragma unroll
  for (int i = 0; i < 2; ++i)
    #pragma unroll
    for (int j = 0; j < 16; ++j) acc[i][j] = f32x4{0,0,0,0};

  for (int kt = 0; kt < 8; ++kt) {
    if (kt) __syncthreads();
    #pragma unroll
    for (int i = 0; i < 4; ++i) {
      const int c = i * 256 + tid;
      gload16(A + (size_t)(m0 + (c >> 3)) * 512 + kt * 64 + (c & 7) * 8, sA + c * 8);
    }
    #pragma unroll
    for (int i = 0; i < 8; ++i) {
      const int c = i * 256 + tid;
      gload16(Bw + (size_t)(c >> 3) * 512 + kt * 64 + (c & 7) * 8, sB + c * 8);
    }
    __syncthreads();
    #pragma unroll
    for (int k0 = 0; k0 < 2; ++k0) {
      short8 af[2];
      #pragma unroll
      for (int mt = 0; mt < 2; ++mt)
        af[mt] = *(const short8*)(sA + (wv * 32 + mt * 16 + rq) * 64 + k0 * 32 + kg * 8);
      #pragma unroll
      for (int nt = 0; nt < 16; ++nt) {
        const short8 bf8 = *(const short8*)(sB + (nt * 16 + rq) * 64 + k0 * 32 + kg * 8);
        #pragma unroll
        for (int mt = 0; mt < 2; ++mt)
          acc[mt][nt] = mfma16(af[mt], bf8, acc[mt][nt]);
      }
    }
  }

  float br[16], g2r[16], b2r[16];
  #pragma unroll
  for (int nt = 0; nt < 16; ++nt) {
    const int col = nt * 16 + rq;
    br[nt] = bias[col]; g2r[nt] = g2[col]; b2r[nt] = b2[col];
  }
  #pragma unroll
  for (int mt = 0; mt < 2; ++mt) {
    #pragma unroll
    for (int r = 0; r < 4; ++r) {
      const int row = m0 + wv * 32 + mt * 16 + kg * 4 + r;
      const u32 g = (u32)(rowbase + row);
      const u32 w = g / 49u; const u32 n = g - w * 49u;
      const int b = w >> 6, win = w & 63, wh = win >> 3, ww = win & 7;
      const u32 rr = n / 7u; const u32 cc = n - rr * 7u;
      int oh = wh * 7 + (int)rr + 3; if (oh >= 56) oh -= 56;
      int ow = ww * 7 + (int)cc + 3; if (ow >= 56) ow -= 56;
      const size_t po = ((size_t)b * 3136 + oh * 56 + ow) * 256;
      float vals[16];
      float s = 0.f;
      #pragma unroll
      for (int nt = 0; nt < 16; ++nt) {
        const float v = acc[mt][nt][r] + br[nt] + x[po + nt * 16 + rq];
        vals[nt] = v; s += v;
      }
      #pragma unroll
      for (int off = 1; off < 16; off <<= 1) s += __shfl_xor(s, off);
      const float mean = s * (1.0f / 256.0f);
      float sq = 0.f;
      #pragma unroll
      for (int nt = 0; nt < 16; ++nt) { const float d_ = vals[nt] - mean; sq += d_ * d_; }
      #pragma unroll
      for (int off = 1; off < 16; off <<= 1) sq += __shfl_xor(sq, off);
      const float rstd = rsqrtf(sq * (1.0f / 256.0f) + 1e-5f);
      #pragma unroll
      for (int nt = 0; nt < 16; ++nt) {
        const int col = nt * 16 + rq;
        out[po + col] = vals[nt];
        xn2[po + col] = f2bf((vals[nt] - mean) * rstd * g2r[nt] + b2r[nt]);
      }
    }
  }
}

// ---------------- fused MLP v2: 4 phases of 256-wide h tiles, h stays in LDS ----------------
// block = 64 rows, 4 waves; wave owns 64 fc1-cols & 64 fc2-outcols per phase.
__global__ __launch_bounds__(256, 2) void fused_mlp(
    const u16* __restrict__ xn2, const u16* __restrict__ w1,
    const float* __restrict__ bf1, const u16* __restrict__ w2,
    const float* __restrict__ bf2v, float* __restrict__ out)
{
  __shared__ __align__(16) u16 sX[64 * 256];   // 32 KB, chunk-swizzled
  __shared__ __align__(16) u16 sH[64 * 256];   // 32 KB, chunk-swizzled

  const int m0 = blockIdx.x * 64;
  const int tid = threadIdx.x;
  const int wv = tid >> 6, lane = tid & 63;
  const int rq = lane & 15, kg = lane >> 4;

  // stage xn2 panel (pre-swizzled global source, linear LDS dest)
  #pragma unroll
  for (int i = 0; i < 8; ++i) {
    const int c = i * 256 + tid;
    const int row = c >> 5, ch = c & 31;
    const int sch = (ch & 24) | ((ch ^ row) & 7);
    gload16(xn2 + (size_t)(m0 + row) * 256 + sch * 8, sX + c * 8);
  }

  f32x4 acc2[4][4];
  #pragma unroll
  for (int i = 0; i < 4; ++i)
    #pragma unroll
    for (int j = 0; j < 4; ++j) acc2[i][j] = f32x4{0,0,0,0};

  __syncthreads();

  for (int t = 0; t < 4; ++t) {
    // ---- fc1: this wave's 64 h-cols of phase t ----
    f32x4 a1[4][4];
    #pragma unroll
    for (int i = 0; i < 4; ++i)
      #pragma unroll
      for (int j = 0; j < 4; ++j) a1[i][j] = f32x4{0,0,0,0};
    #pragma unroll
    for (int ks = 0; ks < 8; ++ks) {
      short8 bfr[4];
      #pragma unroll
      for (int nt = 0; nt < 4; ++nt)
        bfr[nt] = *(const short8*)(w1 + (size_t)(t * 256 + wv * 64 + nt * 16 + rq) * 256 + ks * 32 + kg * 8);
      #pragma unroll
      for (int mt = 0; mt < 4; ++mt) {
        const int R = mt * 16 + rq;
        const int wk = ks * 4 + kg;
        const short8 af = *(const short8*)(sX + R * 256 + ((wk & 24) | ((wk ^ R) & 7)) * 8);
        #pragma unroll
        for (int nt = 0; nt < 4; ++nt)
          a1[mt][nt] = mfma16(af, bfr[nt], a1[mt][nt]);
      }
    }
    __syncthreads();   // prior phase's fc2 reads of sH complete
    // ---- bias + GELU, write h tile (swizzled) ----
    #pragma unroll
    for (int nt = 0; nt < 4; ++nt) {
      const int col = wv * 64 + nt * 16 + rq;     // local 0..255
      const float bb = bf1[t * 256 + col];
      const int c = col >> 3;
      #pragma unroll
      for (int mt = 0; mt < 4; ++mt)
        #pragma unroll
        for (int r = 0; r < 4; ++r) {
          const int row = mt * 16 + kg * 4 + r;
          sH[row * 256 + ((c & 24) | ((c ^ row) & 7)) * 8 + (col & 7)] =
              f2bf(gelu_t(a1[mt][nt][r] + bb));
        }
    }
    __syncthreads();   // h tile visible
    // ---- fc2 partial: 64 rows x this wave's 64 outcols, k = t*256..+256 ----
    #pragma unroll
    for (int ks = 0; ks < 8; ++ks) {
      short8 bfr2[4];
      #pragma unroll
      for (int nt = 0; nt < 4; ++nt)
        bfr2[nt] = *(const short8*)(w2 + (size_t)(wv * 64 + nt * 16 + rq) * 1024 + t * 256 + ks * 32 + kg * 8);
      #pragma unroll
      for (int mt = 0; mt < 4; ++mt) {
        const int R = mt * 16 + rq;
        const int wk = ks * 4 + kg;
        const short8 af = *(const short8*)(sH + R * 256 + ((wk & 24) | ((wk ^ R) & 7)) * 8);
        #pragma unroll
        for (int nt = 0; nt < 4; ++nt)
          acc2[mt][nt] = mfma16(af, bfr2[nt], acc2[mt][nt]);
      }
    }
  }

  // ---- epilogue: + b_fc2 + residual RMW ----
  #pragma unroll
  for (int nt = 0; nt < 4; ++nt) {
    const int col = wv * 64 + nt * 16 + rq;
    const float bb = bf2v[col];
    #pragma unroll
    for (int mt = 0; mt < 4; ++mt)
      #pragma unroll
      for (int r = 0; r < 4; ++r) {
        float* p = out + (size_t)(m0 + mt * 16 + kg * 4 + r) * 256 + col;
        *p = acc2[mt][nt][r] + bb + *p;
      }
  }
}

extern "C" void kernel_launch(void* const* d_in, const int* in_sizes, int n_in,
                              void* d_out, int out_size, void* d_ws, size_t ws_size,
                              hipStream_t stream) {
  const float* x      = (const float*)d_in[0];
  const float* y      = (const float*)d_in[1];
  const float* g1     = (const float*)d_in[2];
  const float* b1     = (const float*)d_in[3];
  const float* rpb    = (const float*)d_in[4];
  const float* w_qkv  = (const float*)d_in[5];
  const float* b_qkv  = (const float*)d_in[6];
  const float* w_proj = (const float*)d_in[7];
  const float* b_proj = (const float*)d_in[8];
  const float* g2     = (const float*)d_in[9];
  const float* b2     = (const float*)d_in[10];
  const float* w_fc1  = (const float*)d_in[11];
  const float* b_fc1  = (const float*)d_in[12];
  const float* w_fc2  = (const float*)d_in[13];
  const float* b_fc2  = (const float*)d_in[14];
  float* out = (float*)d_out;

  u16* wsp = (u16*)d_ws;
  u16* wqkv_bf  = wsp;                       //  786432
  u16* wproj_bf = wsp + 786432;              //  131072
  u16* wfc1_bf  = wsp + 917504;              //  262144
  u16* wfc2_bf  = wsp + 1179648;             //  262144
  float* btab   = (float*)(wsp + 1441792);   //  131072 f32
  u16* xn2      = wsp + 1703936;             //  25690112
  u16* XYc      = wsp + 27394048;            //  12845056 (25088 x 512)
  u16* qkvc     = wsp + 40239104;            //  24 planes x 25088 x 64

  convk<<<768, 256, 0, stream>>>(w_qkv,  wqkv_bf,  196608);
  convk<<<128, 256, 0, stream>>>(w_proj, wproj_bf, 32768);
  convk<<<256, 256, 0, stream>>>(w_fc1,  wfc1_bf,  65536);
  convk<<<256, 256, 0, stream>>>(w_fc2,  wfc2_bf,  65536);
  btab_build<<<32, 256, 0, stream>>>(rpb, btab);

  for (int c = 0; c < 4; ++c) {
    ln_gather<<<6272, 256, 0, stream>>>(x, y, g1, b1, XYc, c * CHUNK_ROWS);
    qkv_gemm<<<dim3(12, 196), 256, 0, stream>>>(XYc, wqkv_bf, b_qkv, qkvc);
    attn3<<<1024, 256, 0, stream>>>(qkvc, btab, XYc, c * 512);
    projln<<<196, 256, 0, stream>>>(XYc, wproj_bf, b_proj, x, g2, b2, out, xn2, c * CHUNK_ROWS);
  }

  fused_mlp<<<1568, 256, 0, stream>>>(xn2, wfc1_bf, b_fc1, wfc2_bf, b_fc2, out);
}